// Round 2
// baseline (2329.502 us; speedup 1.0000x reference)
//
#include <hip/hip_runtime.h>

#define DEVINL __device__ __forceinline__

static constexpr int BLK = 256;

DEVINL float sigmoidf_(float x) { return 1.0f / (1.0f + __expf(-x)); }
// stable tanh: large +x -> exp=inf -> 1-0 = 1; large -x -> exp=0 -> 1-2 = -1
DEVINL float tanh_fast(float x) { return 1.0f - 2.0f / (__expf(2.0f * x) + 1.0f); }

DEVINL float dot4(float4 w, float a, float b, float c, float d) {
  return w.x * a + w.y * b + w.z * c + w.w * d;
}

__global__ void zero_kernel(float* __restrict__ deg, int* __restrict__ cnt,
                            int* __restrict__ fillcnt, int N) {
  int i = blockIdx.x * blockDim.x + threadIdx.x;
  if (i < N) { deg[i] = 0.0f; cnt[i] = 0; fillcnt[i] = 0; }
}

// feat_n = feat / rowsum(feat); write to featn (for LSTM windows) and buf0 cols [0,8)
__global__ void norm_kernel(const float* __restrict__ feat, float* __restrict__ featn,
                            float* __restrict__ buf0, int N) {
  int n = blockIdx.x * blockDim.x + threadIdx.x;
  if (n >= N) return;
  const float4* fp = (const float4*)(feat + (size_t)n * 8);
  float4 a = fp[0], b = fp[1];
  float s = a.x + a.y + a.z + a.w + b.x + b.y + b.z + b.w;
  float r = 1.0f / s;
  a.x *= r; a.y *= r; a.z *= r; a.w *= r;
  b.x *= r; b.y *= r; b.z *= r; b.w *= r;
  float4* on = (float4*)(featn + (size_t)n * 8);
  on[0] = a; on[1] = b;
  float4* o0 = (float4*)(buf0 + (size_t)n * 24);
  o0[0] = a; o0[1] = b;
}

// one thread per node; 5-step LSTM over window feat_n[max(0,n-5) .. ), right-zero-padded.
// writes h_last into buf0 cols [8,24)
// __launch_bounds__(256, 2): VGPR budget 256 — the 64-VGPR default spilled h/c/hn
// to scratch (2.23 GB HBM traffic, 966 us). Grid is only ~1.5 waves/SIMD anyway.
__global__ __launch_bounds__(256, 2) void lstm_kernel(
    const float* __restrict__ featn,
    const float* __restrict__ W_ih, const float* __restrict__ W_hh,
    const float* __restrict__ b_ih, const float* __restrict__ b_hh,
    float* __restrict__ buf0, int N) {
  // float4 LDS views -> ds_read_b128 (4x fewer LDS ops than scalar reads)
  __shared__ float4 sWih[64 * 2];   // [4H=64 rows][8 floats] as 2 float4 per row
  __shared__ float4 sWhh[64 * 4];   // [64 rows][16 floats] as 4 float4 per row
  __shared__ float sb[64];
  {
    const float4* gWih = (const float4*)W_ih;
    const float4* gWhh = (const float4*)W_hh;
    for (int i = threadIdx.x; i < 64 * 2; i += blockDim.x) sWih[i] = gWih[i];
    for (int i = threadIdx.x; i < 64 * 4; i += blockDim.x) sWhh[i] = gWhh[i];
    for (int i = threadIdx.x; i < 64; i += blockDim.x) sb[i] = b_ih[i] + b_hh[i];
  }
  __syncthreads();
  int n = blockIdx.x * blockDim.x + threadIdx.x;
  if (n >= N) return;
  float h[16], c[16];
#pragma unroll
  for (int j = 0; j < 16; ++j) { h[j] = 0.0f; c[j] = 0.0f; }
  const int start = (n >= 5) ? (n - 5) : 0;
  const int nvalid = (n < 5) ? n : 5;
#pragma unroll
  for (int t = 0; t < 5; ++t) {
    float4 x0, x1;
    if (t < nvalid) {
      const float4* xr = (const float4*)(featn + (size_t)(start + t) * 8);
      x0 = xr[0]; x1 = xr[1];
    } else {
      x0 = make_float4(0.f, 0.f, 0.f, 0.f);
      x1 = x0;
    }
    float hn[16];
#pragma unroll
    for (int j = 0; j < 16; ++j) {
      float g[4];
#pragma unroll
      for (int gg = 0; gg < 4; ++gg) {
        const int row = 16 * gg + j;
        float acc = sb[row];
        float4 wa = sWih[row * 2 + 0];
        float4 wb = sWih[row * 2 + 1];
        acc += dot4(wa, x0.x, x0.y, x0.z, x0.w);
        acc += dot4(wb, x1.x, x1.y, x1.z, x1.w);
        float4 w0 = sWhh[row * 4 + 0];
        float4 w1 = sWhh[row * 4 + 1];
        float4 w2 = sWhh[row * 4 + 2];
        float4 w3 = sWhh[row * 4 + 3];
        acc += dot4(w0, h[0], h[1], h[2], h[3]);
        acc += dot4(w1, h[4], h[5], h[6], h[7]);
        acc += dot4(w2, h[8], h[9], h[10], h[11]);
        acc += dot4(w3, h[12], h[13], h[14], h[15]);
        g[gg] = acc;
      }
      float cn = sigmoidf_(g[1]) * c[j] + sigmoidf_(g[0]) * tanh_fast(g[2]);
      c[j] = cn;
      hn[j] = sigmoidf_(g[3]) * tanh_fast(cn);
    }
#pragma unroll
    for (int j = 0; j < 16; ++j) h[j] = hn[j];
  }
  float* out = buf0 + (size_t)n * 24 + 8;
#pragma unroll
  for (int j = 0; j < 16; ++j) out[j] = h[j];
}

__global__ void deg_kernel(const int* __restrict__ src, const float* __restrict__ w,
                           float* __restrict__ deg, int E) {
  int e = blockIdx.x * blockDim.x + threadIdx.x;
  if (e < E) atomicAdd(&deg[src[e]], w[e]);
}

__global__ void count_kernel(const int* __restrict__ dst, int* __restrict__ cnt, int E) {
  int e = blockIdx.x * blockDim.x + threadIdx.x;
  if (e < E) atomicAdd(&cnt[dst[e]], 1);
}

// single-block exclusive scan of cnt[N] -> rowptr[N+1]
__global__ void scan_kernel(const int* __restrict__ cnt, int* __restrict__ rowptr,
                            int N, int E) {
  __shared__ int part[1024];
  int t = threadIdx.x;
  int chunk = (N + 1023) / 1024;
  int lo = t * chunk;
  int hi = lo + chunk; if (hi > N) hi = N; if (lo > N) lo = N;
  int s = 0;
  for (int i = lo; i < hi; ++i) s += cnt[i];
  part[t] = s;
  __syncthreads();
  for (int d = 1; d < 1024; d <<= 1) {
    int v = (t >= d) ? part[t - d] : 0;
    __syncthreads();
    part[t] += v;
    __syncthreads();
  }
  int run = (t == 0) ? 0 : part[t - 1];
  for (int i = lo; i < hi; ++i) { rowptr[i] = run; run += cnt[i]; }
  if (t == 0) rowptr[N] = E;
}

__global__ void fill_kernel(const int* __restrict__ src, const int* __restrict__ dst,
                            const float* __restrict__ w, const float* __restrict__ deg,
                            const int* __restrict__ rowptr, int* __restrict__ fillcnt,
                            int* __restrict__ col, float* __restrict__ wcsr, int E) {
  int e = blockIdx.x * blockDim.x + threadIdx.x;
  if (e >= E) return;
  int d = dst[e], s = src[e];
  int pos = atomicAdd(&fillcnt[d], 1);
  int idx = rowptr[d] + pos;
  col[idx] = s;
  wcsr[idx] = w[e] * rsqrtf(deg[s] * deg[d]);
}

// M[row, col] = sum_k X[row,k] * W[k,col]
template <int DIN, int DOUT>
__global__ void gemm_kernel(const float* __restrict__ X, const float* __restrict__ W,
                            float* __restrict__ M, int N) {
  int gid = blockIdx.x * blockDim.x + threadIdx.x;
  int row = gid / DOUT, cj = gid % DOUT;
  if (row >= N) return;
  const float* xr = X + (size_t)row * DIN;
  float acc = 0.0f;
#pragma unroll
  for (int k = 0; k < DIN; ++k) acc += xr[k] * W[k * DOUT + cj];
  M[(size_t)row * DOUT + cj] = acc;
}

// out[row, lane] = act( sum_{e in CSR row} wcsr[e]*m[col[e], lane] + bias[lane] )
template <int DOUT, bool ACT>
__global__ void gather_kernel(const float* __restrict__ m, const int* __restrict__ rowptr,
                              const int* __restrict__ col, const float* __restrict__ wcsr,
                              const float* __restrict__ bias, float* __restrict__ out, int N) {
  int gid = blockIdx.x * blockDim.x + threadIdx.x;
  int row = gid / DOUT, lane = gid % DOUT;
  if (row >= N) return;
  int lo = rowptr[row], hi = rowptr[row + 1];
  float acc = 0.0f;
  for (int e = lo; e < hi; ++e) {
    int s = col[e];
    float w = wcsr[e];
    acc += w * m[(size_t)s * DOUT + lane];
  }
  acc += bias[lane];
  if (ACT) acc = (acc >= 0.0f) ? acc : 0.01f * acc;
  out[(size_t)row * DOUT + lane] = acc;
}

extern "C" void kernel_launch(void* const* d_in, const int* in_sizes, int n_in,
                              void* d_out, int out_size, void* d_ws, size_t ws_size,
                              hipStream_t stream) {
  const float* feat = (const float*)d_in[0];
  const int* esrc   = (const int*)d_in[1];
  const int* edst   = (const int*)d_in[2];
  const float* ew   = (const float*)d_in[3];
  const float* W_ih = (const float*)d_in[4];
  const float* W_hh = (const float*)d_in[5];
  const float* b_ih = (const float*)d_in[6];
  const float* b_hh = (const float*)d_in[7];
  const float* W0   = (const float*)d_in[8];
  const float* b0   = (const float*)d_in[9];
  const float* W1   = (const float*)d_in[10];
  const float* b1   = (const float*)d_in[11];
  const float* W2   = (const float*)d_in[12];
  const float* b2   = (const float*)d_in[13];
  const int N = in_sizes[0] / 8;
  const int E = in_sizes[1];
  float* out = (float*)d_out;

  // workspace layout (floats): buf0[N*24] | bufM[N*64] | bufA[N*64] | deg[N] |
  //                            rowptr[N+1] | col[E] | wcsr[E]     (~74 MB total)
  float* buf0 = (float*)d_ws;
  float* bufM = buf0 + (size_t)N * 24;
  float* bufA = bufM + (size_t)N * 64;
  float* deg  = bufA + (size_t)N * 64;
  int* rowptr = (int*)(deg + N);
  int* col    = rowptr + (N + 1);
  float* wcsr = (float*)(col + E);
  // aliases: cnt/fillcnt live in bufM (dead before GEMM0 writes it);
  //          featn lives in bufA (dead before gather0 writes it)
  int* cnt     = (int*)bufM;
  int* fillcnt = cnt + N;
  float* featn = bufA;

  const int gN = (N + BLK - 1) / BLK;
  const int gE = (E + BLK - 1) / BLK;
  const int gN64 = (N * 64 + BLK - 1) / BLK;
  const int gN32 = (N * 32 + BLK - 1) / BLK;

  zero_kernel<<<gN, BLK, 0, stream>>>(deg, cnt, fillcnt, N);
  norm_kernel<<<gN, BLK, 0, stream>>>(feat, featn, buf0, N);
  lstm_kernel<<<gN, BLK, 0, stream>>>(featn, W_ih, W_hh, b_ih, b_hh, buf0, N);
  deg_kernel<<<gE, BLK, 0, stream>>>(esrc, ew, deg, E);
  count_kernel<<<gE, BLK, 0, stream>>>(edst, cnt, E);
  scan_kernel<<<1, 1024, 0, stream>>>(cnt, rowptr, N, E);
  fill_kernel<<<gE, BLK, 0, stream>>>(esrc, edst, ew, deg, rowptr, fillcnt, col, wcsr, E);

  gemm_kernel<24, 64><<<gN64, BLK, 0, stream>>>(buf0, W0, bufM, N);
  gather_kernel<64, true><<<gN64, BLK, 0, stream>>>(bufM, rowptr, col, wcsr, b0, bufA, N);
  gemm_kernel<64, 64><<<gN64, BLK, 0, stream>>>(bufA, W1, bufM, N);
  gather_kernel<64, true><<<gN64, BLK, 0, stream>>>(bufM, rowptr, col, wcsr, b1, bufA, N);
  gemm_kernel<64, 32><<<gN32, BLK, 0, stream>>>(bufA, W2, bufM, N);
  gather_kernel<32, false><<<gN32, BLK, 0, stream>>>(bufM, rowptr, col, wcsr, b2, out, N);
}

// Round 3
// 1020.240 us; speedup vs baseline: 2.2833x; 2.2833x over previous
//
#include <hip/hip_runtime.h>

#define DEVINL __device__ __forceinline__

static constexpr int BLK = 256;

DEVINL float sigmoidf_(float x) { return 1.0f / (1.0f + __expf(-x)); }
// stable tanh: large +x -> exp=inf -> 1-0 = 1; large -x -> exp=0 -> 1-2 = -1
DEVINL float tanh_fast(float x) { return 1.0f - 2.0f / (__expf(2.0f * x) + 1.0f); }

DEVINL float dot4(float4 w, float a, float b, float c, float d) {
  return w.x * a + w.y * b + w.z * c + w.w * d;
}

__global__ void zero_kernel(float* __restrict__ deg, int* __restrict__ cnt,
                            int* __restrict__ fillcnt, int N) {
  int i = blockIdx.x * blockDim.x + threadIdx.x;
  if (i < N) { deg[i] = 0.0f; cnt[i] = 0; fillcnt[i] = 0; }
}

// feat_n = feat / rowsum(feat); write to featn (for LSTM windows) and buf0 cols [0,8)
__global__ void norm_kernel(const float* __restrict__ feat, float* __restrict__ featn,
                            float* __restrict__ buf0, int N) {
  int n = blockIdx.x * blockDim.x + threadIdx.x;
  if (n >= N) return;
  const float4* fp = (const float4*)(feat + (size_t)n * 8);
  float4 a = fp[0], b = fp[1];
  float s = a.x + a.y + a.z + a.w + b.x + b.y + b.z + b.w;
  float r = 1.0f / s;
  a.x *= r; a.y *= r; a.z *= r; a.w *= r;
  b.x *= r; b.y *= r; b.z *= r; b.w *= r;
  float4* on = (float4*)(featn + (size_t)n * 8);
  on[0] = a; on[1] = b;
  float4* o0 = (float4*)(buf0 + (size_t)n * 24);
  o0[0] = a; o0[1] = b;
}

// Wave-cooperative LSTM: 16 lanes per node, lane j owns h[j],c[j] (2 floats).
// Weights for rows {j, 16+j, 32+j, 48+j} live in 24 float4 registers per lane
// (loaded once, L1-broadcast). h-vector broadcast via 16 __shfl per timestep.
// No per-thread arrays with >4 elements -> no scratch spill (rounds 1-2 showed
// the one-thread-per-node version spilled ~16KB/thread = 2.9 GB HBM traffic).
__global__ __launch_bounds__(256, 2) void lstm_kernel(
    const float* __restrict__ featn,
    const float* __restrict__ W_ih, const float* __restrict__ W_hh,
    const float* __restrict__ b_ih, const float* __restrict__ b_hh,
    float* __restrict__ buf0, int N) {
  const int tid = blockIdx.x * blockDim.x + threadIdx.x;
  const int node = tid >> 4;   // 16 lanes per node
  const int j = tid & 15;      // hidden index owned by this lane
  if (node >= N) return;
  const int lanebase = threadIdx.x & 48;  // group base lane within the wave

  float4 wia[4], wib[4];                    // W_ih rows (8 floats each)
  float4 wh0[4], wh1[4], wh2[4], wh3[4];    // W_hh rows (16 floats each)
  float bias[4];
#pragma unroll
  for (int g = 0; g < 4; ++g) {
    const int row = 16 * g + j;
    const float4* wi = (const float4*)(W_ih + row * 8);
    wia[g] = wi[0]; wib[g] = wi[1];
    const float4* wh = (const float4*)(W_hh + row * 16);
    wh0[g] = wh[0]; wh1[g] = wh[1]; wh2[g] = wh[2]; wh3[g] = wh[3];
    bias[g] = b_ih[row] + b_hh[row];
  }

  float h = 0.0f, c = 0.0f;
  const int start = (node >= 5) ? (node - 5) : 0;
  const int nvalid = (node < 5) ? node : 5;
#pragma unroll
  for (int t = 0; t < 5; ++t) {
    float4 x0, x1;
    if (t < nvalid) {
      const float4* xr = (const float4*)(featn + (size_t)(start + t) * 8);
      x0 = xr[0]; x1 = xr[1];
    } else {
      x0 = make_float4(0.f, 0.f, 0.f, 0.f);
      x1 = x0;
    }
    // broadcast full h vector of this node's 16 lanes
    float hb[16];
#pragma unroll
    for (int k = 0; k < 16; ++k) hb[k] = __shfl(h, lanebase + k, 64);
    float g0 = bias[0], g1 = bias[1], g2 = bias[2], g3 = bias[3];
    g0 += dot4(wia[0], x0.x, x0.y, x0.z, x0.w) + dot4(wib[0], x1.x, x1.y, x1.z, x1.w);
    g1 += dot4(wia[1], x0.x, x0.y, x0.z, x0.w) + dot4(wib[1], x1.x, x1.y, x1.z, x1.w);
    g2 += dot4(wia[2], x0.x, x0.y, x0.z, x0.w) + dot4(wib[2], x1.x, x1.y, x1.z, x1.w);
    g3 += dot4(wia[3], x0.x, x0.y, x0.z, x0.w) + dot4(wib[3], x1.x, x1.y, x1.z, x1.w);
    g0 += dot4(wh0[0], hb[0], hb[1], hb[2], hb[3])   + dot4(wh1[0], hb[4], hb[5], hb[6], hb[7])
        + dot4(wh2[0], hb[8], hb[9], hb[10], hb[11]) + dot4(wh3[0], hb[12], hb[13], hb[14], hb[15]);
    g1 += dot4(wh0[1], hb[0], hb[1], hb[2], hb[3])   + dot4(wh1[1], hb[4], hb[5], hb[6], hb[7])
        + dot4(wh2[1], hb[8], hb[9], hb[10], hb[11]) + dot4(wh3[1], hb[12], hb[13], hb[14], hb[15]);
    g2 += dot4(wh0[2], hb[0], hb[1], hb[2], hb[3])   + dot4(wh1[2], hb[4], hb[5], hb[6], hb[7])
        + dot4(wh2[2], hb[8], hb[9], hb[10], hb[11]) + dot4(wh3[2], hb[12], hb[13], hb[14], hb[15]);
    g3 += dot4(wh0[3], hb[0], hb[1], hb[2], hb[3])   + dot4(wh1[3], hb[4], hb[5], hb[6], hb[7])
        + dot4(wh2[3], hb[8], hb[9], hb[10], hb[11]) + dot4(wh3[3], hb[12], hb[13], hb[14], hb[15]);
    const float ig = sigmoidf_(g0);
    const float fg = sigmoidf_(g1);
    const float gg = tanh_fast(g2);
    const float og = sigmoidf_(g3);
    c = fg * c + ig * gg;
    h = og * tanh_fast(c);
  }
  buf0[(size_t)node * 24 + 8 + j] = h;  // 16 lanes -> 64B contiguous
}

__global__ void deg_kernel(const int* __restrict__ src, const float* __restrict__ w,
                           float* __restrict__ deg, int E) {
  int e = blockIdx.x * blockDim.x + threadIdx.x;
  if (e < E) atomicAdd(&deg[src[e]], w[e]);
}

__global__ void count_kernel(const int* __restrict__ dst, int* __restrict__ cnt, int E) {
  int e = blockIdx.x * blockDim.x + threadIdx.x;
  if (e < E) atomicAdd(&cnt[dst[e]], 1);
}

// single-block exclusive scan of cnt[N] -> rowptr[N+1]
__global__ void scan_kernel(const int* __restrict__ cnt, int* __restrict__ rowptr,
                            int N, int E) {
  __shared__ int part[1024];
  int t = threadIdx.x;
  int chunk = (N + 1023) / 1024;
  int lo = t * chunk;
  int hi = lo + chunk; if (hi > N) hi = N; if (lo > N) lo = N;
  int s = 0;
  for (int i = lo; i < hi; ++i) s += cnt[i];
  part[t] = s;
  __syncthreads();
  for (int d = 1; d < 1024; d <<= 1) {
    int v = (t >= d) ? part[t - d] : 0;
    __syncthreads();
    part[t] += v;
    __syncthreads();
  }
  int run = (t == 0) ? 0 : part[t - 1];
  for (int i = lo; i < hi; ++i) { rowptr[i] = run; run += cnt[i]; }
  if (t == 0) rowptr[N] = E;
}

__global__ void fill_kernel(const int* __restrict__ src, const int* __restrict__ dst,
                            const float* __restrict__ w, const float* __restrict__ deg,
                            const int* __restrict__ rowptr, int* __restrict__ fillcnt,
                            int* __restrict__ col, float* __restrict__ wcsr, int E) {
  int e = blockIdx.x * blockDim.x + threadIdx.x;
  if (e >= E) return;
  int d = dst[e], s = src[e];
  int pos = atomicAdd(&fillcnt[d], 1);
  int idx = rowptr[d] + pos;
  col[idx] = s;
  wcsr[idx] = w[e] * rsqrtf(deg[s] * deg[d]);
}

// M[row, col] = sum_k X[row,k] * W[k,col]
template <int DIN, int DOUT>
__global__ void gemm_kernel(const float* __restrict__ X, const float* __restrict__ W,
                            float* __restrict__ M, int N) {
  int gid = blockIdx.x * blockDim.x + threadIdx.x;
  int row = gid / DOUT, cj = gid % DOUT;
  if (row >= N) return;
  const float* xr = X + (size_t)row * DIN;
  float acc = 0.0f;
#pragma unroll
  for (int k = 0; k < DIN; ++k) acc += xr[k] * W[k * DOUT + cj];
  M[(size_t)row * DOUT + cj] = acc;
}

// out[row, lane] = act( sum_{e in CSR row} wcsr[e]*m[col[e], lane] + bias[lane] )
template <int DOUT, bool ACT>
__global__ void gather_kernel(const float* __restrict__ m, const int* __restrict__ rowptr,
                              const int* __restrict__ col, const float* __restrict__ wcsr,
                              const float* __restrict__ bias, float* __restrict__ out, int N) {
  int gid = blockIdx.x * blockDim.x + threadIdx.x;
  int row = gid / DOUT, lane = gid % DOUT;
  if (row >= N) return;
  int lo = rowptr[row], hi = rowptr[row + 1];
  float acc = 0.0f;
  for (int e = lo; e < hi; ++e) {
    int s = col[e];
    float w = wcsr[e];
    acc += w * m[(size_t)s * DOUT + lane];
  }
  acc += bias[lane];
  if (ACT) acc = (acc >= 0.0f) ? acc : 0.01f * acc;
  out[(size_t)row * DOUT + lane] = acc;
}

extern "C" void kernel_launch(void* const* d_in, const int* in_sizes, int n_in,
                              void* d_out, int out_size, void* d_ws, size_t ws_size,
                              hipStream_t stream) {
  const float* feat = (const float*)d_in[0];
  const int* esrc   = (const int*)d_in[1];
  const int* edst   = (const int*)d_in[2];
  const float* ew   = (const float*)d_in[3];
  const float* W_ih = (const float*)d_in[4];
  const float* W_hh = (const float*)d_in[5];
  const float* b_ih = (const float*)d_in[6];
  const float* b_hh = (const float*)d_in[7];
  const float* W0   = (const float*)d_in[8];
  const float* b0   = (const float*)d_in[9];
  const float* W1   = (const float*)d_in[10];
  const float* b1   = (const float*)d_in[11];
  const float* W2   = (const float*)d_in[12];
  const float* b2   = (const float*)d_in[13];
  const int N = in_sizes[0] / 8;
  const int E = in_sizes[1];
  float* out = (float*)d_out;

  // workspace layout (floats): buf0[N*24] | bufM[N*64] | bufA[N*64] | deg[N] |
  //                            rowptr[N+1] | col[E] | wcsr[E]     (~74 MB total)
  float* buf0 = (float*)d_ws;
  float* bufM = buf0 + (size_t)N * 24;
  float* bufA = bufM + (size_t)N * 64;
  float* deg  = bufA + (size_t)N * 64;
  int* rowptr = (int*)(deg + N);
  int* col    = rowptr + (N + 1);
  float* wcsr = (float*)(col + E);
  // aliases: cnt/fillcnt live in bufM (dead before GEMM0 writes it);
  //          featn lives in bufA (dead before gather0 writes it)
  int* cnt     = (int*)bufM;
  int* fillcnt = cnt + N;
  float* featn = bufA;

  const int gN = (N + BLK - 1) / BLK;
  const int gE = (E + BLK - 1) / BLK;
  const int gN16 = ((size_t)N * 16 + BLK - 1) / BLK;   // lstm: 16 lanes/node
  const int gN64 = (N * 64 + BLK - 1) / BLK;
  const int gN32 = (N * 32 + BLK - 1) / BLK;

  zero_kernel<<<gN, BLK, 0, stream>>>(deg, cnt, fillcnt, N);
  norm_kernel<<<gN, BLK, 0, stream>>>(feat, featn, buf0, N);
  lstm_kernel<<<gN16, BLK, 0, stream>>>(featn, W_ih, W_hh, b_ih, b_hh, buf0, N);
  deg_kernel<<<gE, BLK, 0, stream>>>(esrc, ew, deg, E);
  count_kernel<<<gE, BLK, 0, stream>>>(edst, cnt, E);
  scan_kernel<<<1, 1024, 0, stream>>>(cnt, rowptr, N, E);
  fill_kernel<<<gE, BLK, 0, stream>>>(esrc, edst, ew, deg, rowptr, fillcnt, col, wcsr, E);

  gemm_kernel<24, 64><<<gN64, BLK, 0, stream>>>(buf0, W0, bufM, N);
  gather_kernel<64, true><<<gN64, BLK, 0, stream>>>(bufM, rowptr, col, wcsr, b0, bufA, N);
  gemm_kernel<64, 64><<<gN64, BLK, 0, stream>>>(bufA, W1, bufM, N);
  gather_kernel<64, true><<<gN64, BLK, 0, stream>>>(bufM, rowptr, col, wcsr, b1, bufA, N);
  gemm_kernel<64, 32><<<gN32, BLK, 0, stream>>>(bufA, W2, bufM, N);
  gather_kernel<32, false><<<gN32, BLK, 0, stream>>>(bufM, rowptr, col, wcsr, b2, out, N);
}

// Round 4
// 594.615 us; speedup vs baseline: 3.9177x; 1.7158x over previous
//
#include <hip/hip_runtime.h>

#define DEVINL __device__ __forceinline__

static constexpr int BLK = 256;

DEVINL float sigmoidf_(float x) { return 1.0f / (1.0f + __expf(-x)); }
// stable tanh: large +x -> exp=inf -> 1-0 = 1; large -x -> exp=0 -> 1-2 = -1
DEVINL float tanh_fast(float x) { return 1.0f - 2.0f / (__expf(2.0f * x) + 1.0f); }

DEVINL float dot4(float4 w, float a, float b, float c, float d) {
  return w.x * a + w.y * b + w.z * c + w.w * d;
}

__global__ void zero_kernel(float* __restrict__ deg, int* __restrict__ cnt,
                            int* __restrict__ fillcnt, int N) {
  int i = blockIdx.x * blockDim.x + threadIdx.x;
  if (i < N) { deg[i] = 0.0f; cnt[i] = 0; fillcnt[i] = 0; }
}

// feat_n = feat / rowsum(feat); write to featn (for LSTM windows) and buf0 cols [0,8)
__global__ void norm_kernel(const float* __restrict__ feat, float* __restrict__ featn,
                            float* __restrict__ buf0, int N) {
  int n = blockIdx.x * blockDim.x + threadIdx.x;
  if (n >= N) return;
  const float4* fp = (const float4*)(feat + (size_t)n * 8);
  float4 a = fp[0], b = fp[1];
  float s = a.x + a.y + a.z + a.w + b.x + b.y + b.z + b.w;
  float r = 1.0f / s;
  a.x *= r; a.y *= r; a.z *= r; a.w *= r;
  b.x *= r; b.y *= r; b.z *= r; b.w *= r;
  float4* on = (float4*)(featn + (size_t)n * 8);
  on[0] = a; on[1] = b;
  float4* o0 = (float4*)(buf0 + (size_t)n * 24);
  o0[0] = a; o0[1] = b;
}

// Wave-cooperative LSTM: 16 lanes per node, lane j owns h[j],c[j].
// Weights for rows {j,16+j,32+j,48+j} in 24 float4 regs/lane; h broadcast via __shfl.
// (one-thread-per-node version spilled ~16KB/thread -> 2.9 GB scratch traffic)
__global__ __launch_bounds__(256, 2) void lstm_kernel(
    const float* __restrict__ featn,
    const float* __restrict__ W_ih, const float* __restrict__ W_hh,
    const float* __restrict__ b_ih, const float* __restrict__ b_hh,
    float* __restrict__ buf0, int N) {
  const int tid = blockIdx.x * blockDim.x + threadIdx.x;
  const int node = tid >> 4;
  const int j = tid & 15;
  if (node >= N) return;
  const int lanebase = threadIdx.x & 48;

  float4 wia[4], wib[4];
  float4 wh0[4], wh1[4], wh2[4], wh3[4];
  float bias[4];
#pragma unroll
  for (int g = 0; g < 4; ++g) {
    const int row = 16 * g + j;
    const float4* wi = (const float4*)(W_ih + row * 8);
    wia[g] = wi[0]; wib[g] = wi[1];
    const float4* wh = (const float4*)(W_hh + row * 16);
    wh0[g] = wh[0]; wh1[g] = wh[1]; wh2[g] = wh[2]; wh3[g] = wh[3];
    bias[g] = b_ih[row] + b_hh[row];
  }

  float h = 0.0f, c = 0.0f;
  const int start = (node >= 5) ? (node - 5) : 0;
  const int nvalid = (node < 5) ? node : 5;
#pragma unroll
  for (int t = 0; t < 5; ++t) {
    float4 x0, x1;
    if (t < nvalid) {
      const float4* xr = (const float4*)(featn + (size_t)(start + t) * 8);
      x0 = xr[0]; x1 = xr[1];
    } else {
      x0 = make_float4(0.f, 0.f, 0.f, 0.f);
      x1 = x0;
    }
    float hb[16];
#pragma unroll
    for (int k = 0; k < 16; ++k) hb[k] = __shfl(h, lanebase + k, 64);
    float g0 = bias[0], g1 = bias[1], g2 = bias[2], g3 = bias[3];
    g0 += dot4(wia[0], x0.x, x0.y, x0.z, x0.w) + dot4(wib[0], x1.x, x1.y, x1.z, x1.w);
    g1 += dot4(wia[1], x0.x, x0.y, x0.z, x0.w) + dot4(wib[1], x1.x, x1.y, x1.z, x1.w);
    g2 += dot4(wia[2], x0.x, x0.y, x0.z, x0.w) + dot4(wib[2], x1.x, x1.y, x1.z, x1.w);
    g3 += dot4(wia[3], x0.x, x0.y, x0.z, x0.w) + dot4(wib[3], x1.x, x1.y, x1.z, x1.w);
    g0 += dot4(wh0[0], hb[0], hb[1], hb[2], hb[3])   + dot4(wh1[0], hb[4], hb[5], hb[6], hb[7])
        + dot4(wh2[0], hb[8], hb[9], hb[10], hb[11]) + dot4(wh3[0], hb[12], hb[13], hb[14], hb[15]);
    g1 += dot4(wh0[1], hb[0], hb[1], hb[2], hb[3])   + dot4(wh1[1], hb[4], hb[5], hb[6], hb[7])
        + dot4(wh2[1], hb[8], hb[9], hb[10], hb[11]) + dot4(wh3[1], hb[12], hb[13], hb[14], hb[15]);
    g2 += dot4(wh0[2], hb[0], hb[1], hb[2], hb[3])   + dot4(wh1[2], hb[4], hb[5], hb[6], hb[7])
        + dot4(wh2[2], hb[8], hb[9], hb[10], hb[11]) + dot4(wh3[2], hb[12], hb[13], hb[14], hb[15]);
    g3 += dot4(wh0[3], hb[0], hb[1], hb[2], hb[3])   + dot4(wh1[3], hb[4], hb[5], hb[6], hb[7])
        + dot4(wh2[3], hb[8], hb[9], hb[10], hb[11]) + dot4(wh3[3], hb[12], hb[13], hb[14], hb[15]);
    const float ig = sigmoidf_(g0);
    const float fg = sigmoidf_(g1);
    const float gg = tanh_fast(g2);
    const float og = sigmoidf_(g3);
    c = fg * c + ig * gg;
    h = og * tanh_fast(c);
  }
  buf0[(size_t)node * 24 + 8 + j] = h;
}

// fused: deg[src] += w  and  cnt[dst] += 1  in one pass over the edge list
__global__ void degcnt_kernel(const int* __restrict__ src, const int* __restrict__ dst,
                              const float* __restrict__ w, float* __restrict__ deg,
                              int* __restrict__ cnt, int E) {
  int e = blockIdx.x * blockDim.x + threadIdx.x;
  if (e >= E) return;
  atomicAdd(&deg[src[e]], w[e]);
  atomicAdd(&cnt[dst[e]], 1);
}

// ---- 3-stage parallel exclusive scan of cnt[N] -> rowptr[N+1] ----
// stage 1: 1024 elems/block; per-element local exclusive scan + block total
__global__ void scan_block_kernel(const int* __restrict__ cnt, int* __restrict__ rowptr,
                                  int* __restrict__ blocksum, int N) {
  __shared__ int sd[256];
  const int t = threadIdx.x;
  const int base = blockIdx.x * 1024 + t * 4;
  int c0 = 0, c1 = 0, c2 = 0, c3 = 0;
  if (base + 3 < N) {
    int4 v = *(const int4*)(cnt + base);
    c0 = v.x; c1 = v.y; c2 = v.z; c3 = v.w;
  } else {
    if (base < N) c0 = cnt[base];
    if (base + 1 < N) c1 = cnt[base + 1];
    if (base + 2 < N) c2 = cnt[base + 2];
  }
  int s = c0 + c1 + c2 + c3;
  sd[t] = s;
  __syncthreads();
  for (int d = 1; d < 256; d <<= 1) {
    int v = (t >= d) ? sd[t - d] : 0;
    __syncthreads();
    sd[t] += v;
    __syncthreads();
  }
  if (t == 255) blocksum[blockIdx.x] = sd[255];
  int p = sd[t] - s;  // exclusive
  if (base < N)     { rowptr[base] = p;     p += c0; }
  if (base + 1 < N) { rowptr[base + 1] = p; p += c1; }
  if (base + 2 < N) { rowptr[base + 2] = p; p += c2; }
  if (base + 3 < N) { rowptr[base + 3] = p; }
}

// stage 2: exclusive-scan the (<=256*chunk) block totals in one block
__global__ void scan_top_kernel(int* __restrict__ blocksum, int nb) {
  __shared__ int sd[256];
  const int t = threadIdx.x;
  const int chunk = (nb + 255) / 256;
  int lo = t * chunk, hi = lo + chunk;
  if (lo > nb) lo = nb;
  if (hi > nb) hi = nb;
  int s = 0;
  for (int i = lo; i < hi; ++i) s += blocksum[i];
  sd[t] = s;
  __syncthreads();
  for (int d = 1; d < 256; d <<= 1) {
    int v = (t >= d) ? sd[t - d] : 0;
    __syncthreads();
    sd[t] += v;
    __syncthreads();
  }
  int run = sd[t] - s;
  for (int i = lo; i < hi; ++i) { int v = blocksum[i]; blocksum[i] = run; run += v; }
}

// stage 3: add block offsets; also write rowptr[N]=E
__global__ void scan_add_kernel(int* __restrict__ rowptr, const int* __restrict__ blocksum,
                                int N, int E) {
  const int off = blocksum[blockIdx.x];
  const int base = blockIdx.x * 1024 + threadIdx.x * 4;
#pragma unroll
  for (int k = 0; k < 4; ++k)
    if (base + k < N) rowptr[base + k] += off;
  if (blockIdx.x == 0 && threadIdx.x == 0) rowptr[N] = E;
}

// CSR fill with packed (col, norm_w) int2 entries
__global__ void fill_kernel(const int* __restrict__ src, const int* __restrict__ dst,
                            const float* __restrict__ w, const float* __restrict__ deg,
                            const int* __restrict__ rowptr, int* __restrict__ fillcnt,
                            int2* __restrict__ epk, int E) {
  int e = blockIdx.x * blockDim.x + threadIdx.x;
  if (e >= E) return;
  int d = dst[e], s = src[e];
  int pos = atomicAdd(&fillcnt[d], 1);
  int idx = rowptr[d] + pos;
  int2 pk;
  pk.x = s;
  pk.y = __float_as_int(w[e] * rsqrtf(deg[s] * deg[d]));
  epk[idx] = pk;
}

// M[row, :] = X[row, :] @ W ; DOUT/4 threads per row, float4 outputs
template <int DIN, int DOUT>
__global__ void gemm_kernel(const float* __restrict__ X, const float* __restrict__ W,
                            float* __restrict__ M, int N) {
  constexpr int SUBS = DOUT / 4;
  int gid = blockIdx.x * blockDim.x + threadIdx.x;
  int row = gid / SUBS, sub = gid % SUBS;
  if (row >= N) return;
  const float* xr = X + (size_t)row * DIN;
  const float4* W4 = (const float4*)W;
  float4 acc = make_float4(0.f, 0.f, 0.f, 0.f);
#pragma unroll
  for (int k = 0; k < DIN; ++k) {
    float xk = xr[k];
    float4 w4 = W4[k * SUBS + sub];
    acc.x += xk * w4.x; acc.y += xk * w4.y; acc.z += xk * w4.z; acc.w += xk * w4.w;
  }
  ((float4*)M)[(size_t)row * SUBS + sub] = acc;
}

// out[row, sub*4..] = act( sum_e w_e * m[col_e, sub*4..] + bias ) ; float4 gathers
template <int DOUT, bool ACT>
__global__ void gather_kernel(const float* __restrict__ m, const int* __restrict__ rowptr,
                              const int2* __restrict__ epk, const float* __restrict__ bias,
                              float* __restrict__ out, int N) {
  constexpr int SUBS = DOUT / 4;
  int gid = blockIdx.x * blockDim.x + threadIdx.x;
  int row = gid / SUBS, sub = gid % SUBS;
  if (row >= N) return;
  const int lo = rowptr[row], hi = rowptr[row + 1];
  const float4* m4 = (const float4*)m;
  float4 acc = make_float4(0.f, 0.f, 0.f, 0.f);
  for (int e = lo; e < hi; ++e) {
    int2 pk = epk[e];
    float w = __int_as_float(pk.y);
    float4 v = m4[(size_t)pk.x * SUBS + sub];
    acc.x += w * v.x; acc.y += w * v.y; acc.z += w * v.z; acc.w += w * v.w;
  }
  float4 b4 = ((const float4*)bias)[sub];
  acc.x += b4.x; acc.y += b4.y; acc.z += b4.z; acc.w += b4.w;
  if (ACT) {
    acc.x = (acc.x >= 0.f) ? acc.x : 0.01f * acc.x;
    acc.y = (acc.y >= 0.f) ? acc.y : 0.01f * acc.y;
    acc.z = (acc.z >= 0.f) ? acc.z : 0.01f * acc.z;
    acc.w = (acc.w >= 0.f) ? acc.w : 0.01f * acc.w;
  }
  ((float4*)out)[(size_t)row * SUBS + sub] = acc;
}

extern "C" void kernel_launch(void* const* d_in, const int* in_sizes, int n_in,
                              void* d_out, int out_size, void* d_ws, size_t ws_size,
                              hipStream_t stream) {
  const float* feat = (const float*)d_in[0];
  const int* esrc   = (const int*)d_in[1];
  const int* edst   = (const int*)d_in[2];
  const float* ew   = (const float*)d_in[3];
  const float* W_ih = (const float*)d_in[4];
  const float* W_hh = (const float*)d_in[5];
  const float* b_ih = (const float*)d_in[6];
  const float* b_hh = (const float*)d_in[7];
  const float* W0   = (const float*)d_in[8];
  const float* b0   = (const float*)d_in[9];
  const float* W1   = (const float*)d_in[10];
  const float* b1   = (const float*)d_in[11];
  const float* W2   = (const float*)d_in[12];
  const float* b2   = (const float*)d_in[13];
  const int N = in_sizes[0] / 8;
  const int E = in_sizes[1];
  float* out = (float*)d_out;

  // workspace (floats): buf0[24N] | bufM[64N] | bufA[64N] | deg[N] | rowptr[N+2] | epk[2E]
  float* buf0 = (float*)d_ws;
  float* bufM = buf0 + (size_t)N * 24;
  float* bufA = bufM + (size_t)N * 64;
  float* deg  = bufA + (size_t)N * 64;
  int* rowptr = (int*)(deg + N);
  int2* epk   = (int2*)(rowptr + N + 2);  // N even -> 8B aligned
  // aliases: cnt/fillcnt in bufM (dead before gemm0 writes it);
  //          featn in bufA[0,8N); blocksum in bufA at +16N (dead before gather0)
  int* cnt      = (int*)bufM;
  int* fillcnt  = cnt + N;
  float* featn  = bufA;
  int* blocksum = (int*)(bufA + (size_t)N * 16);

  const int gN = (N + BLK - 1) / BLK;
  const int gE = (E + BLK - 1) / BLK;
  const int gN16 = ((size_t)N * 16 + BLK - 1) / BLK;
  const int gN8  = ((size_t)N * 8 + BLK - 1) / BLK;
  const int nb = (N + 1023) / 1024;  // scan blocks (98 for N=100k; scan_top handles <=256*chunk)

  zero_kernel<<<gN, BLK, 0, stream>>>(deg, cnt, fillcnt, N);
  norm_kernel<<<gN, BLK, 0, stream>>>(feat, featn, buf0, N);
  lstm_kernel<<<gN16, BLK, 0, stream>>>(featn, W_ih, W_hh, b_ih, b_hh, buf0, N);
  degcnt_kernel<<<gE, BLK, 0, stream>>>(esrc, edst, ew, deg, cnt, E);
  scan_block_kernel<<<nb, 256, 0, stream>>>(cnt, rowptr, blocksum, N);
  scan_top_kernel<<<1, 256, 0, stream>>>(blocksum, nb);
  scan_add_kernel<<<nb, 256, 0, stream>>>(rowptr, blocksum, N, E);
  fill_kernel<<<gE, BLK, 0, stream>>>(esrc, edst, ew, deg, rowptr, fillcnt, epk, E);

  gemm_kernel<24, 64><<<gN16, BLK, 0, stream>>>(buf0, W0, bufM, N);
  gather_kernel<64, true><<<gN16, BLK, 0, stream>>>(bufM, rowptr, epk, b0, bufA, N);
  gemm_kernel<64, 64><<<gN16, BLK, 0, stream>>>(bufA, W1, bufM, N);
  gather_kernel<64, true><<<gN16, BLK, 0, stream>>>(bufM, rowptr, epk, b1, bufA, N);
  gemm_kernel<64, 32><<<gN8, BLK, 0, stream>>>(bufA, W2, bufM, N);
  gather_kernel<32, false><<<gN8, BLK, 0, stream>>>(bufM, rowptr, epk, b2, out, N);
}

// Round 5
// 459.789 us; speedup vs baseline: 5.0665x; 1.2932x over previous
//
#include <hip/hip_runtime.h>

#define DEVINL __device__ __forceinline__

static constexpr int BLK = 256;

DEVINL float sigmoidf_(float x) { return 1.0f / (1.0f + __expf(-x)); }
// stable tanh: large +x -> exp=inf -> 1-0 = 1; large -x -> exp=0 -> 1-2 = -1
DEVINL float tanh_fast(float x) { return 1.0f - 2.0f / (__expf(2.0f * x) + 1.0f); }

DEVINL float dot4(float4 w, float a, float b, float c, float d) {
  return w.x * a + w.y * b + w.z * c + w.w * d;
}

__global__ void zero_kernel(float* __restrict__ deg, int* __restrict__ cnt, int N) {
  int i = blockIdx.x * blockDim.x + threadIdx.x;
  if (i < N) { deg[i] = 0.0f; cnt[i] = 0; }
}

// feat_n = feat / rowsum(feat); write to featn (for LSTM windows) and buf0 cols [0,8)
__global__ void norm_kernel(const float* __restrict__ feat, float* __restrict__ featn,
                            float* __restrict__ buf0, int N) {
  int n = blockIdx.x * blockDim.x + threadIdx.x;
  if (n >= N) return;
  const float4* fp = (const float4*)(feat + (size_t)n * 8);
  float4 a = fp[0], b = fp[1];
  float s = a.x + a.y + a.z + a.w + b.x + b.y + b.z + b.w;
  float r = 1.0f / s;
  a.x *= r; a.y *= r; a.z *= r; a.w *= r;
  b.x *= r; b.y *= r; b.z *= r; b.w *= r;
  float4* on = (float4*)(featn + (size_t)n * 8);
  on[0] = a; on[1] = b;
  float4* o0 = (float4*)(buf0 + (size_t)n * 24);
  o0[0] = a; o0[1] = b;
}

// Wave-cooperative LSTM: 16 lanes per node, lane j owns h[j],c[j].
// Weights for rows {j,16+j,32+j,48+j} in 24 float4 regs/lane; h broadcast via __shfl.
// (one-thread-per-node version spilled ~16KB/thread -> 2.9 GB scratch traffic)
__global__ __launch_bounds__(256, 2) void lstm_kernel(
    const float* __restrict__ featn,
    const float* __restrict__ W_ih, const float* __restrict__ W_hh,
    const float* __restrict__ b_ih, const float* __restrict__ b_hh,
    float* __restrict__ buf0, int N) {
  const int tid = blockIdx.x * blockDim.x + threadIdx.x;
  const int node = tid >> 4;
  const int j = tid & 15;
  if (node >= N) return;
  const int lanebase = threadIdx.x & 48;

  float4 wia[4], wib[4];
  float4 wh0[4], wh1[4], wh2[4], wh3[4];
  float bias[4];
#pragma unroll
  for (int g = 0; g < 4; ++g) {
    const int row = 16 * g + j;
    const float4* wi = (const float4*)(W_ih + row * 8);
    wia[g] = wi[0]; wib[g] = wi[1];
    const float4* wh = (const float4*)(W_hh + row * 16);
    wh0[g] = wh[0]; wh1[g] = wh[1]; wh2[g] = wh[2]; wh3[g] = wh[3];
    bias[g] = b_ih[row] + b_hh[row];
  }

  float h = 0.0f, c = 0.0f;
  const int start = (node >= 5) ? (node - 5) : 0;
  const int nvalid = (node < 5) ? node : 5;
#pragma unroll
  for (int t = 0; t < 5; ++t) {
    float4 x0, x1;
    if (t < nvalid) {
      const float4* xr = (const float4*)(featn + (size_t)(start + t) * 8);
      x0 = xr[0]; x1 = xr[1];
    } else {
      x0 = make_float4(0.f, 0.f, 0.f, 0.f);
      x1 = x0;
    }
    float hb[16];
#pragma unroll
    for (int k = 0; k < 16; ++k) hb[k] = __shfl(h, lanebase + k, 64);
    float g0 = bias[0], g1 = bias[1], g2 = bias[2], g3 = bias[3];
    g0 += dot4(wia[0], x0.x, x0.y, x0.z, x0.w) + dot4(wib[0], x1.x, x1.y, x1.z, x1.w);
    g1 += dot4(wia[1], x0.x, x0.y, x0.z, x0.w) + dot4(wib[1], x1.x, x1.y, x1.z, x1.w);
    g2 += dot4(wia[2], x0.x, x0.y, x0.z, x0.w) + dot4(wib[2], x1.x, x1.y, x1.z, x1.w);
    g3 += dot4(wia[3], x0.x, x0.y, x0.z, x0.w) + dot4(wib[3], x1.x, x1.y, x1.z, x1.w);
    g0 += dot4(wh0[0], hb[0], hb[1], hb[2], hb[3])   + dot4(wh1[0], hb[4], hb[5], hb[6], hb[7])
        + dot4(wh2[0], hb[8], hb[9], hb[10], hb[11]) + dot4(wh3[0], hb[12], hb[13], hb[14], hb[15]);
    g1 += dot4(wh0[1], hb[0], hb[1], hb[2], hb[3])   + dot4(wh1[1], hb[4], hb[5], hb[6], hb[7])
        + dot4(wh2[1], hb[8], hb[9], hb[10], hb[11]) + dot4(wh3[1], hb[12], hb[13], hb[14], hb[15]);
    g2 += dot4(wh0[2], hb[0], hb[1], hb[2], hb[3])   + dot4(wh1[2], hb[4], hb[5], hb[6], hb[7])
        + dot4(wh2[2], hb[8], hb[9], hb[10], hb[11]) + dot4(wh3[2], hb[12], hb[13], hb[14], hb[15]);
    g3 += dot4(wh0[3], hb[0], hb[1], hb[2], hb[3])   + dot4(wh1[3], hb[4], hb[5], hb[6], hb[7])
        + dot4(wh2[3], hb[8], hb[9], hb[10], hb[11]) + dot4(wh3[3], hb[12], hb[13], hb[14], hb[15]);
    const float ig = sigmoidf_(g0);
    const float fg = sigmoidf_(g1);
    const float gg = tanh_fast(g2);
    const float og = sigmoidf_(g3);
    c = fg * c + ig * gg;
    h = og * tanh_fast(c);
  }
  buf0[(size_t)node * 24 + 8 + j] = h;
}

// One pass over the edge list:
//  - deg[src] += w with wave-segmented reduction over runs of equal src
//    (src is sorted: 16-way same-address atomic contention was serializing the
//    old version at 165us; runs collapse to 1 atomic each)
//  - pos[e] = atomicAdd(cnt[dst], 1) recorded so fill needs no atomics
__global__ void degcnt_kernel(const int* __restrict__ src, const int* __restrict__ dst,
                              const float* __restrict__ w, float* __restrict__ deg,
                              int* __restrict__ cnt, int* __restrict__ pos, int E) {
  const int e = blockIdx.x * blockDim.x + threadIdx.x;
  const int lane = threadIdx.x & 63;
  const bool valid = e < E;
  int s = valid ? src[e] : -1;
  float acc = valid ? w[e] : 0.0f;
  // head flag: start of a run of equal src
  int sprev = __shfl_up(s, 1, 64);
  unsigned f = (lane == 0 || sprev != s) ? 1u : 0u;
  // segmented inclusive scan (head flags reset the sum)
#pragma unroll
  for (int d = 1; d < 64; d <<= 1) {
    float o = __shfl_up(acc, d, 64);
    unsigned fo = __shfl_up(f, d, 64);
    if (lane >= d) {
      if (!f) acc += o;
      f |= fo;
    }
  }
  int snext = __shfl_down(s, 1, 64);
  bool tail = (lane == 63) || (snext != s);
  if (valid && tail) atomicAdd(&deg[s], acc);
  if (valid) pos[e] = atomicAdd(&cnt[dst[e]], 1);
}

// ---- 3-stage parallel exclusive scan of cnt[N] -> rowptr[N+1] ----
__global__ void scan_block_kernel(const int* __restrict__ cnt, int* __restrict__ rowptr,
                                  int* __restrict__ blocksum, int N) {
  __shared__ int sd[256];
  const int t = threadIdx.x;
  const int base = blockIdx.x * 1024 + t * 4;
  int c0 = 0, c1 = 0, c2 = 0, c3 = 0;
  if (base + 3 < N) {
    int4 v = *(const int4*)(cnt + base);
    c0 = v.x; c1 = v.y; c2 = v.z; c3 = v.w;
  } else {
    if (base < N) c0 = cnt[base];
    if (base + 1 < N) c1 = cnt[base + 1];
    if (base + 2 < N) c2 = cnt[base + 2];
  }
  int s = c0 + c1 + c2 + c3;
  sd[t] = s;
  __syncthreads();
  for (int d = 1; d < 256; d <<= 1) {
    int v = (t >= d) ? sd[t - d] : 0;
    __syncthreads();
    sd[t] += v;
    __syncthreads();
  }
  if (t == 255) blocksum[blockIdx.x] = sd[255];
  int p = sd[t] - s;  // exclusive
  if (base < N)     { rowptr[base] = p;     p += c0; }
  if (base + 1 < N) { rowptr[base + 1] = p; p += c1; }
  if (base + 2 < N) { rowptr[base + 2] = p; p += c2; }
  if (base + 3 < N) { rowptr[base + 3] = p; }
}

__global__ void scan_top_kernel(int* __restrict__ blocksum, int nb) {
  __shared__ int sd[256];
  const int t = threadIdx.x;
  const int chunk = (nb + 255) / 256;
  int lo = t * chunk, hi = lo + chunk;
  if (lo > nb) lo = nb;
  if (hi > nb) hi = nb;
  int s = 0;
  for (int i = lo; i < hi; ++i) s += blocksum[i];
  sd[t] = s;
  __syncthreads();
  for (int d = 1; d < 256; d <<= 1) {
    int v = (t >= d) ? sd[t - d] : 0;
    __syncthreads();
    sd[t] += v;
    __syncthreads();
  }
  int run = sd[t] - s;
  for (int i = lo; i < hi; ++i) { int v = blocksum[i]; blocksum[i] = run; run += v; }
}

__global__ void scan_add_kernel(int* __restrict__ rowptr, const int* __restrict__ blocksum,
                                int N, int E) {
  const int off = blocksum[blockIdx.x];
  const int base = blockIdx.x * 1024 + threadIdx.x * 4;
#pragma unroll
  for (int k = 0; k < 4; ++k)
    if (base + k < N) rowptr[base + k] += off;
  if (blockIdx.x == 0 && threadIdx.x == 0) rowptr[N] = E;
}

// CSR fill, no atomics: slot precomputed as rowptr[dst] + pos
__global__ void fill_kernel(const int* __restrict__ src, const int* __restrict__ dst,
                            const float* __restrict__ w, const float* __restrict__ deg,
                            const int* __restrict__ rowptr, const int* __restrict__ pos,
                            int2* __restrict__ epk, int E) {
  int e = blockIdx.x * blockDim.x + threadIdx.x;
  if (e >= E) return;
  int d = dst[e], s = src[e];
  int idx = rowptr[d] + pos[e];
  int2 pk;
  pk.x = s;
  pk.y = __float_as_int(w[e] * rsqrtf(deg[s] * deg[d]));
  epk[idx] = pk;
}

// M[row, :] = X[row, :] @ W ; DOUT/4 threads per row, float4 outputs
template <int DIN, int DOUT>
__global__ void gemm_kernel(const float* __restrict__ X, const float* __restrict__ W,
                            float* __restrict__ M, int N) {
  constexpr int SUBS = DOUT / 4;
  int gid = blockIdx.x * blockDim.x + threadIdx.x;
  int row = gid / SUBS, sub = gid % SUBS;
  if (row >= N) return;
  const float* xr = X + (size_t)row * DIN;
  const float4* W4 = (const float4*)W;
  float4 acc = make_float4(0.f, 0.f, 0.f, 0.f);
#pragma unroll
  for (int k = 0; k < DIN; ++k) {
    float xk = xr[k];
    float4 w4 = W4[k * SUBS + sub];
    acc.x += xk * w4.x; acc.y += xk * w4.y; acc.z += xk * w4.z; acc.w += xk * w4.w;
  }
  ((float4*)M)[(size_t)row * SUBS + sub] = acc;
}

// out[row, sub*4..] = act( sum_e w_e * m[col_e, sub*4..] + bias ) ; float4 gathers
template <int DOUT, bool ACT>
__global__ void gather_kernel(const float* __restrict__ m, const int* __restrict__ rowptr,
                              const int2* __restrict__ epk, const float* __restrict__ bias,
                              float* __restrict__ out, int N) {
  constexpr int SUBS = DOUT / 4;
  int gid = blockIdx.x * blockDim.x + threadIdx.x;
  int row = gid / SUBS, sub = gid % SUBS;
  if (row >= N) return;
  const int lo = rowptr[row], hi = rowptr[row + 1];
  const float4* m4 = (const float4*)m;
  float4 acc = make_float4(0.f, 0.f, 0.f, 0.f);
  for (int e = lo; e < hi; ++e) {
    int2 pk = epk[e];
    float w = __int_as_float(pk.y);
    float4 v = m4[(size_t)pk.x * SUBS + sub];
    acc.x += w * v.x; acc.y += w * v.y; acc.z += w * v.z; acc.w += w * v.w;
  }
  float4 b4 = ((const float4*)bias)[sub];
  acc.x += b4.x; acc.y += b4.y; acc.z += b4.z; acc.w += b4.w;
  if (ACT) {
    acc.x = (acc.x >= 0.f) ? acc.x : 0.01f * acc.x;
    acc.y = (acc.y >= 0.f) ? acc.y : 0.01f * acc.y;
    acc.z = (acc.z >= 0.f) ? acc.z : 0.01f * acc.z;
    acc.w = (acc.w >= 0.f) ? acc.w : 0.01f * acc.w;
  }
  ((float4*)out)[(size_t)row * SUBS + sub] = acc;
}

extern "C" void kernel_launch(void* const* d_in, const int* in_sizes, int n_in,
                              void* d_out, int out_size, void* d_ws, size_t ws_size,
                              hipStream_t stream) {
  const float* feat = (const float*)d_in[0];
  const int* esrc   = (const int*)d_in[1];
  const int* edst   = (const int*)d_in[2];
  const float* ew   = (const float*)d_in[3];
  const float* W_ih = (const float*)d_in[4];
  const float* W_hh = (const float*)d_in[5];
  const float* b_ih = (const float*)d_in[6];
  const float* b_hh = (const float*)d_in[7];
  const float* W0   = (const float*)d_in[8];
  const float* b0   = (const float*)d_in[9];
  const float* W1   = (const float*)d_in[10];
  const float* b1   = (const float*)d_in[11];
  const float* W2   = (const float*)d_in[12];
  const float* b2   = (const float*)d_in[13];
  const int N = in_sizes[0] / 8;
  const int E = in_sizes[1];
  float* out = (float*)d_out;

  // workspace (floats): buf0[24N] | bufM[64N] | bufA[64N] | deg[N] | rowptr[N+2] | epk[2E]
  float* buf0 = (float*)d_ws;
  float* bufM = buf0 + (size_t)N * 24;
  float* bufA = bufM + (size_t)N * 64;
  float* deg  = bufA + (size_t)N * 64;
  int* rowptr = (int*)(deg + N);
  int2* epk   = (int2*)(rowptr + N + 2);  // N even -> 8B aligned
  // aliases: cnt[N] + pos[E] in bufM (dead before gemm0 writes it);
  //          featn in bufA[0,8N); blocksum in bufA at +16N (dead before gather0)
  int* cnt      = (int*)bufM;
  int* pos      = cnt + N;
  float* featn  = bufA;
  int* blocksum = (int*)(bufA + (size_t)N * 16);

  const int gN = (N + BLK - 1) / BLK;
  const int gE = (E + BLK - 1) / BLK;
  const int gN16 = ((size_t)N * 16 + BLK - 1) / BLK;
  const int gN8  = ((size_t)N * 8 + BLK - 1) / BLK;
  const int nb = (N + 1023) / 1024;

  zero_kernel<<<gN, BLK, 0, stream>>>(deg, cnt, N);
  norm_kernel<<<gN, BLK, 0, stream>>>(feat, featn, buf0, N);
  lstm_kernel<<<gN16, BLK, 0, stream>>>(featn, W_ih, W_hh, b_ih, b_hh, buf0, N);
  degcnt_kernel<<<gE, BLK, 0, stream>>>(esrc, edst, ew, deg, cnt, pos, E);
  scan_block_kernel<<<nb, 256, 0, stream>>>(cnt, rowptr, blocksum, N);
  scan_top_kernel<<<1, 256, 0, stream>>>(blocksum, nb);
  scan_add_kernel<<<nb, 256, 0, stream>>>(rowptr, blocksum, N, E);
  fill_kernel<<<gE, BLK, 0, stream>>>(esrc, edst, ew, deg, rowptr, pos, epk, E);

  gemm_kernel<24, 64><<<gN16, BLK, 0, stream>>>(buf0, W0, bufM, N);
  gather_kernel<64, true><<<gN16, BLK, 0, stream>>>(bufM, rowptr, epk, b0, bufA, N);
  gemm_kernel<64, 64><<<gN16, BLK, 0, stream>>>(bufA, W1, bufM, N);
  gather_kernel<64, true><<<gN16, BLK, 0, stream>>>(bufM, rowptr, epk, b1, bufA, N);
  gemm_kernel<64, 32><<<gN8, BLK, 0, stream>>>(bufA, W2, bufM, N);
  gather_kernel<32, false><<<gN8, BLK, 0, stream>>>(bufM, rowptr, epk, b2, out, N);
}

// Round 6
// 381.400 us; speedup vs baseline: 6.1078x; 1.2055x over previous
//
#include <hip/hip_runtime.h>

#define DEVINL __device__ __forceinline__

static constexpr int BLK = 256;

DEVINL float sigmoidf_(float x) { return 1.0f / (1.0f + __expf(-x)); }
// stable tanh: large +x -> exp=inf -> 1-0 = 1; large -x -> exp=0 -> 1-2 = -1
DEVINL float tanh_fast(float x) { return 1.0f - 2.0f / (__expf(2.0f * x) + 1.0f); }

DEVINL float dot4(float4 w, float a, float b, float c, float d) {
  return w.x * a + w.y * b + w.z * c + w.w * d;
}

// fused: zero deg/cnt + row-normalize feat -> featn and buf0 cols [0,8)
__global__ void prep_kernel(const float* __restrict__ feat, float* __restrict__ featn,
                            float* __restrict__ buf0, float* __restrict__ deg,
                            int* __restrict__ cnt, int N) {
  int n = blockIdx.x * blockDim.x + threadIdx.x;
  if (n >= N) return;
  deg[n] = 0.0f;
  cnt[n] = 0;
  const float4* fp = (const float4*)(feat + (size_t)n * 8);
  float4 a = fp[0], b = fp[1];
  float s = a.x + a.y + a.z + a.w + b.x + b.y + b.z + b.w;
  float r = 1.0f / s;
  a.x *= r; a.y *= r; a.z *= r; a.w *= r;
  b.x *= r; b.y *= r; b.z *= r; b.w *= r;
  float4* on = (float4*)(featn + (size_t)n * 8);
  on[0] = a; on[1] = b;
  float4* o0 = (float4*)(buf0 + (size_t)n * 24);
  o0[0] = a; o0[1] = b;
}

// Fused LSTM + edge pass, 4:1 block interleave so atomic-latency-bound edge
// waves co-reside with VALU-bound LSTM waves (hides the atomic round-trip).
//  - LSTM: 16 lanes/node, lane j owns h[j],c[j]; weights in regs; h via __shfl.
//  - edge blocks: 4 edges/thread -> 4 independent atomicAdd-with-return (ILP),
//    deg via wave-segmented reduction (src sorted -> 1 atomic per run),
//    seg-scan VALU work placed between atomic issue and pos write.
__global__ __launch_bounds__(256, 2) void lstm_edge_kernel(
    const float* __restrict__ featn,
    const float* __restrict__ W_ih, const float* __restrict__ W_hh,
    const float* __restrict__ b_ih, const float* __restrict__ b_hh,
    float* __restrict__ buf0, int N,
    const int* __restrict__ src, const int* __restrict__ dst,
    const float* __restrict__ ew, float* __restrict__ deg,
    int* __restrict__ cnt, int* __restrict__ pos, int E) {
  const int b = blockIdx.x;
  const int g = b / 5, r = b - g * 5;
  if (r < 4) {
    // ---- LSTM branch ----
    const int tid = (g * 4 + r) * 256 + (int)threadIdx.x;
    const int node = tid >> 4;
    const int j = tid & 15;
    if (node >= N) return;
    const int lanebase = threadIdx.x & 48;

    float4 wia[4], wib[4];
    float4 wh0[4], wh1[4], wh2[4], wh3[4];
    float bias[4];
#pragma unroll
    for (int gg = 0; gg < 4; ++gg) {
      const int row = 16 * gg + j;
      const float4* wi = (const float4*)(W_ih + row * 8);
      wia[gg] = wi[0]; wib[gg] = wi[1];
      const float4* wh = (const float4*)(W_hh + row * 16);
      wh0[gg] = wh[0]; wh1[gg] = wh[1]; wh2[gg] = wh[2]; wh3[gg] = wh[3];
      bias[gg] = b_ih[row] + b_hh[row];
    }

    float h = 0.0f, c = 0.0f;
    const int start = (node >= 5) ? (node - 5) : 0;
    const int nvalid = (node < 5) ? node : 5;
#pragma unroll
    for (int t = 0; t < 5; ++t) {
      float4 x0, x1;
      if (t < nvalid) {
        const float4* xr = (const float4*)(featn + (size_t)(start + t) * 8);
        x0 = xr[0]; x1 = xr[1];
      } else {
        x0 = make_float4(0.f, 0.f, 0.f, 0.f);
        x1 = x0;
      }
      float hb[16];
#pragma unroll
      for (int k = 0; k < 16; ++k) hb[k] = __shfl(h, lanebase + k, 64);
      float g0 = bias[0], g1 = bias[1], g2 = bias[2], g3 = bias[3];
      g0 += dot4(wia[0], x0.x, x0.y, x0.z, x0.w) + dot4(wib[0], x1.x, x1.y, x1.z, x1.w);
      g1 += dot4(wia[1], x0.x, x0.y, x0.z, x0.w) + dot4(wib[1], x1.x, x1.y, x1.z, x1.w);
      g2 += dot4(wia[2], x0.x, x0.y, x0.z, x0.w) + dot4(wib[2], x1.x, x1.y, x1.z, x1.w);
      g3 += dot4(wia[3], x0.x, x0.y, x0.z, x0.w) + dot4(wib[3], x1.x, x1.y, x1.z, x1.w);
      g0 += dot4(wh0[0], hb[0], hb[1], hb[2], hb[3])   + dot4(wh1[0], hb[4], hb[5], hb[6], hb[7])
          + dot4(wh2[0], hb[8], hb[9], hb[10], hb[11]) + dot4(wh3[0], hb[12], hb[13], hb[14], hb[15]);
      g1 += dot4(wh0[1], hb[0], hb[1], hb[2], hb[3])   + dot4(wh1[1], hb[4], hb[5], hb[6], hb[7])
          + dot4(wh2[1], hb[8], hb[9], hb[10], hb[11]) + dot4(wh3[1], hb[12], hb[13], hb[14], hb[15]);
      g2 += dot4(wh0[2], hb[0], hb[1], hb[2], hb[3])   + dot4(wh1[2], hb[4], hb[5], hb[6], hb[7])
          + dot4(wh2[2], hb[8], hb[9], hb[10], hb[11]) + dot4(wh3[2], hb[12], hb[13], hb[14], hb[15]);
      g3 += dot4(wh0[3], hb[0], hb[1], hb[2], hb[3])   + dot4(wh1[3], hb[4], hb[5], hb[6], hb[7])
          + dot4(wh2[3], hb[8], hb[9], hb[10], hb[11]) + dot4(wh3[3], hb[12], hb[13], hb[14], hb[15]);
      const float ig = sigmoidf_(g0);
      const float fg = sigmoidf_(g1);
      const float gg2 = tanh_fast(g2);
      const float og = sigmoidf_(g3);
      c = fg * c + ig * gg2;
      h = og * tanh_fast(c);
    }
    buf0[(size_t)node * 24 + 8 + j] = h;
  } else {
    // ---- edge branch: 1024 consecutive edges per block, 4 per thread ----
    const int base = g * 1024 + (int)threadIdx.x;
    const int lane = threadIdx.x & 63;
    int dv[4], sv[4];
    float wv[4];
    bool v[4];
#pragma unroll
    for (int k = 0; k < 4; ++k) {
      const int e = base + k * 256;
      v[k] = e < E;
      dv[k] = v[k] ? dst[e] : 0;
      sv[k] = v[k] ? src[e] : -1;
      wv[k] = v[k] ? ew[e] : 0.0f;
    }
    int p[4];
#pragma unroll
    for (int k = 0; k < 4; ++k)
      if (v[k]) p[k] = atomicAdd(&cnt[dv[k]], 1);
    // deg segmented reduction (VALU/shfl) overlaps the atomic round-trips
#pragma unroll
    for (int k = 0; k < 4; ++k) {
      int s = sv[k];
      float acc = wv[k];
      int sprev = __shfl_up(s, 1, 64);
      unsigned f = (lane == 0 || sprev != s) ? 1u : 0u;
#pragma unroll
      for (int d = 1; d < 64; d <<= 1) {
        float o = __shfl_up(acc, d, 64);
        unsigned fo = __shfl_up(f, d, 64);
        if (lane >= d) {
          if (!f) acc += o;
          f |= fo;
        }
      }
      int snext = __shfl_down(s, 1, 64);
      bool tail = (lane == 63) || (snext != s);
      if (v[k] && tail && s >= 0) atomicAdd(&deg[s], acc);
    }
#pragma unroll
    for (int k = 0; k < 4; ++k)
      if (v[k]) pos[base + k * 256] = p[k];
  }
}

// ---- 3-stage parallel exclusive scan of cnt[N] -> rowptr[N+1] ----
__global__ void scan_block_kernel(const int* __restrict__ cnt, int* __restrict__ rowptr,
                                  int* __restrict__ blocksum, int N) {
  __shared__ int sd[256];
  const int t = threadIdx.x;
  const int base = blockIdx.x * 1024 + t * 4;
  int c0 = 0, c1 = 0, c2 = 0, c3 = 0;
  if (base + 3 < N) {
    int4 v = *(const int4*)(cnt + base);
    c0 = v.x; c1 = v.y; c2 = v.z; c3 = v.w;
  } else {
    if (base < N) c0 = cnt[base];
    if (base + 1 < N) c1 = cnt[base + 1];
    if (base + 2 < N) c2 = cnt[base + 2];
  }
  int s = c0 + c1 + c2 + c3;
  sd[t] = s;
  __syncthreads();
  for (int d = 1; d < 256; d <<= 1) {
    int v = (t >= d) ? sd[t - d] : 0;
    __syncthreads();
    sd[t] += v;
    __syncthreads();
  }
  if (t == 255) blocksum[blockIdx.x] = sd[255];
  int p = sd[t] - s;  // exclusive
  if (base < N)     { rowptr[base] = p;     p += c0; }
  if (base + 1 < N) { rowptr[base + 1] = p; p += c1; }
  if (base + 2 < N) { rowptr[base + 2] = p; p += c2; }
  if (base + 3 < N) { rowptr[base + 3] = p; }
}

__global__ void scan_top_kernel(int* __restrict__ blocksum, int nb) {
  __shared__ int sd[256];
  const int t = threadIdx.x;
  const int chunk = (nb + 255) / 256;
  int lo = t * chunk, hi = lo + chunk;
  if (lo > nb) lo = nb;
  if (hi > nb) hi = nb;
  int s = 0;
  for (int i = lo; i < hi; ++i) s += blocksum[i];
  sd[t] = s;
  __syncthreads();
  for (int d = 1; d < 256; d <<= 1) {
    int v = (t >= d) ? sd[t - d] : 0;
    __syncthreads();
    sd[t] += v;
    __syncthreads();
  }
  int run = sd[t] - s;
  for (int i = lo; i < hi; ++i) { int v = blocksum[i]; blocksum[i] = run; run += v; }
}

__global__ void scan_add_kernel(int* __restrict__ rowptr, const int* __restrict__ blocksum,
                                int N, int E) {
  const int off = blocksum[blockIdx.x];
  const int base = blockIdx.x * 1024 + threadIdx.x * 4;
#pragma unroll
  for (int k = 0; k < 4; ++k)
    if (base + k < N) rowptr[base + k] += off;
  if (blockIdx.x == 0 && threadIdx.x == 0) rowptr[N] = E;
}

// CSR fill, no atomics: slot precomputed as rowptr[dst] + pos
__global__ void fill_kernel(const int* __restrict__ src, const int* __restrict__ dst,
                            const float* __restrict__ w, const float* __restrict__ deg,
                            const int* __restrict__ rowptr, const int* __restrict__ pos,
                            int2* __restrict__ epk, int E) {
  int e = blockIdx.x * blockDim.x + threadIdx.x;
  if (e >= E) return;
  int d = dst[e], s = src[e];
  int idx = rowptr[d] + pos[e];
  int2 pk;
  pk.x = s;
  pk.y = __float_as_int(w[e] * rsqrtf(deg[s] * deg[d]));
  epk[idx] = pk;
}

// M[row,:] = X[row,:] @ W (+bias, leaky-relu if BIASACT); DOUT/4 threads/row
template <int DIN, int DOUT, bool BIASACT>
__global__ void gemm_kernel(const float* __restrict__ X, const float* __restrict__ W,
                            const float* __restrict__ bias, float* __restrict__ M, int N) {
  constexpr int SUBS = DOUT / 4;
  int gid = blockIdx.x * blockDim.x + threadIdx.x;
  int row = gid / SUBS, sub = gid % SUBS;
  if (row >= N) return;
  const float* xr = X + (size_t)row * DIN;
  const float4* W4 = (const float4*)W;
  float4 acc = make_float4(0.f, 0.f, 0.f, 0.f);
#pragma unroll
  for (int k = 0; k < DIN; ++k) {
    float xk = xr[k];
    float4 w4 = W4[k * SUBS + sub];
    acc.x += xk * w4.x; acc.y += xk * w4.y; acc.z += xk * w4.z; acc.w += xk * w4.w;
  }
  if (BIASACT) {
    float4 b4 = ((const float4*)bias)[sub];
    acc.x += b4.x; acc.y += b4.y; acc.z += b4.z; acc.w += b4.w;
    acc.x = (acc.x >= 0.f) ? acc.x : 0.01f * acc.x;
    acc.y = (acc.y >= 0.f) ? acc.y : 0.01f * acc.y;
    acc.z = (acc.z >= 0.f) ? acc.z : 0.01f * acc.z;
    acc.w = (acc.w >= 0.f) ? acc.w : 0.01f * acc.w;
  }
  ((float4*)M)[(size_t)row * SUBS + sub] = acc;
}

// out[row,sub*4..] = (opt act)( sum_e w_e * m[col_e, sub*4..] (+ opt bias) )
template <int DOUT, bool BIAS, bool ACT>
__global__ void gather_kernel(const float* __restrict__ m, const int* __restrict__ rowptr,
                              const int2* __restrict__ epk, const float* __restrict__ bias,
                              float* __restrict__ out, int N) {
  constexpr int SUBS = DOUT / 4;
  int gid = blockIdx.x * blockDim.x + threadIdx.x;
  int row = gid / SUBS, sub = gid % SUBS;
  if (row >= N) return;
  const int lo = rowptr[row], hi = rowptr[row + 1];
  const float4* m4 = (const float4*)m;
  float4 acc = make_float4(0.f, 0.f, 0.f, 0.f);
  for (int e = lo; e < hi; ++e) {
    int2 pk = epk[e];
    float w = __int_as_float(pk.y);
    float4 v = m4[(size_t)pk.x * SUBS + sub];
    acc.x += w * v.x; acc.y += w * v.y; acc.z += w * v.z; acc.w += w * v.w;
  }
  if (BIAS) {
    float4 b4 = ((const float4*)bias)[sub];
    acc.x += b4.x; acc.y += b4.y; acc.z += b4.z; acc.w += b4.w;
  }
  if (ACT) {
    acc.x = (acc.x >= 0.f) ? acc.x : 0.01f * acc.x;
    acc.y = (acc.y >= 0.f) ? acc.y : 0.01f * acc.y;
    acc.z = (acc.z >= 0.f) ? acc.z : 0.01f * acc.z;
    acc.w = (acc.w >= 0.f) ? acc.w : 0.01f * acc.w;
  }
  ((float4*)out)[(size_t)row * SUBS + sub] = acc;
}

extern "C" void kernel_launch(void* const* d_in, const int* in_sizes, int n_in,
                              void* d_out, int out_size, void* d_ws, size_t ws_size,
                              hipStream_t stream) {
  const float* feat = (const float*)d_in[0];
  const int* esrc   = (const int*)d_in[1];
  const int* edst   = (const int*)d_in[2];
  const float* ew   = (const float*)d_in[3];
  const float* W_ih = (const float*)d_in[4];
  const float* W_hh = (const float*)d_in[5];
  const float* b_ih = (const float*)d_in[6];
  const float* b_hh = (const float*)d_in[7];
  const float* W0   = (const float*)d_in[8];
  const float* b0   = (const float*)d_in[9];
  const float* W1   = (const float*)d_in[10];
  const float* b1   = (const float*)d_in[11];
  const float* W2   = (const float*)d_in[12];
  const float* b2   = (const float*)d_in[13];
  const int N = in_sizes[0] / 8;
  const int E = in_sizes[1];
  float* out = (float*)d_out;

  // workspace (floats): buf0[24N] | bufM[64N] | bufA[64N] | deg[N] | rowptr[N+2] | epk[2E]
  float* buf0 = (float*)d_ws;
  float* bufM = buf0 + (size_t)N * 24;
  float* bufA = bufM + (size_t)N * 64;
  float* deg  = bufA + (size_t)N * 64;
  int* rowptr = (int*)(deg + N);
  int2* epk   = (int2*)(rowptr + N + 2);
  // aliases: cnt[N]+pos[E] in bufM (dead before gather24 writes agg24 there);
  //          agg24[24N] in bufM (dead before gemmM overwrites bufM);
  //          featn in bufA[0,8N) (dead after lstm); blocksum at bufA+16N
  int* cnt      = (int*)bufM;
  int* pos      = cnt + N;
  float* agg24  = bufM;
  float* featn  = bufA;
  int* blocksum = (int*)(bufA + (size_t)N * 16);

  const int gN = (N + BLK - 1) / BLK;
  const int gE = (E + BLK - 1) / BLK;
  const int gN16 = ((size_t)N * 16 + BLK - 1) / BLK;  // 64-wide kernels (SUBS=16)
  const int gN8  = ((size_t)N * 8 + BLK - 1) / BLK;   // 32-wide kernels (SUBS=8)
  const int gN6  = ((size_t)N * 6 + BLK - 1) / BLK;   // 24-wide gather (SUBS=6)
  const int nb = (N + 1023) / 1024;
  const int lstmBlocks = gN16;                        // 16 threads/node
  const int edgeBlocks = (E + 1023) / 1024;           // 1024 edges/block
  const int nG = ((lstmBlocks + 3) / 4 > edgeBlocks) ? (lstmBlocks + 3) / 4 : edgeBlocks;

  prep_kernel<<<gN, BLK, 0, stream>>>(feat, featn, buf0, deg, cnt, N);
  lstm_edge_kernel<<<nG * 5, BLK, 0, stream>>>(featn, W_ih, W_hh, b_ih, b_hh, buf0, N,
                                               esrc, edst, ew, deg, cnt, pos, E);
  scan_block_kernel<<<nb, 256, 0, stream>>>(cnt, rowptr, blocksum, N);
  scan_top_kernel<<<1, 256, 0, stream>>>(blocksum, nb);
  scan_add_kernel<<<nb, 256, 0, stream>>>(rowptr, blocksum, N, E);
  fill_kernel<<<gE, BLK, 0, stream>>>(esrc, edst, ew, deg, rowptr, pos, epk, E);

  // layer 0: aggregate-first (24-wide) then transform+bias+act
  gather_kernel<24, false, false><<<gN6, BLK, 0, stream>>>(buf0, rowptr, epk, nullptr, agg24, N);
  gemm_kernel<24, 64, true><<<gN16, BLK, 0, stream>>>(agg24, W0, b0, bufA, N);
  // layer 1: transform then aggregate (64-wide both ways)
  gemm_kernel<64, 64, false><<<gN16, BLK, 0, stream>>>(bufA, W1, nullptr, bufM, N);
  gather_kernel<64, true, true><<<gN16, BLK, 0, stream>>>(bufM, rowptr, epk, b1, bufA, N);
  // layer 2: transform (64->32) then aggregate (32-wide)
  gemm_kernel<64, 32, false><<<gN8, BLK, 0, stream>>>(bufA, W2, nullptr, bufM, N);
  gather_kernel<32, true, false><<<gN8, BLK, 0, stream>>>(bufM, rowptr, epk, b2, out, N);
}

// Round 7
// 357.656 us; speedup vs baseline: 6.5132x; 1.0664x over previous
//
#include <hip/hip_runtime.h>

#define DEVINL __device__ __forceinline__

static constexpr int BLK = 256;

DEVINL float sigmoidf_(float x) { return 1.0f / (1.0f + __expf(-x)); }
// stable tanh: large +x -> exp=inf -> 1-0 = 1; large -x -> exp=0 -> 1-2 = -1
DEVINL float tanh_fast(float x) { return 1.0f - 2.0f / (__expf(2.0f * x) + 1.0f); }

DEVINL float dot4(float4 w, float a, float b, float c, float d) {
  return w.x * a + w.y * b + w.z * c + w.w * d;
}
DEVINL float dot44(float4 w, float4 h) {
  return w.x * h.x + w.y * h.y + w.z * h.z + w.w * h.w;
}

// fused: zero deg/cnt + row-normalize feat -> featn and buf0 cols [0,8)
__global__ void prep_kernel(const float* __restrict__ feat, float* __restrict__ featn,
                            float* __restrict__ buf0, float* __restrict__ deg,
                            int* __restrict__ cnt, int N) {
  int n = blockIdx.x * blockDim.x + threadIdx.x;
  if (n >= N) return;
  deg[n] = 0.0f;
  cnt[n] = 0;
  const float4* fp = (const float4*)(feat + (size_t)n * 8);
  float4 a = fp[0], b = fp[1];
  float s = a.x + a.y + a.z + a.w + b.x + b.y + b.z + b.w;
  float r = 1.0f / s;
  a.x *= r; a.y *= r; a.z *= r; a.w *= r;
  b.x *= r; b.y *= r; b.z *= r; b.w *= r;
  float4* on = (float4*)(featn + (size_t)n * 8);
  on[0] = a; on[1] = b;
  float4* o0 = (float4*)(buf0 + (size_t)n * 24);
  o0[0] = a; o0[1] = b;
}

// Fused LSTM + edge pass, 4:1 block interleave (atomic-latency edge waves hide
// under VALU-bound LSTM waves).
// LSTM h-broadcast via LDS (1 ds_write + 4 ds_read_b128, wave-internal, no
// barrier) instead of 16 ds_bpermute: the 16-lane node groups never cross a
// wave boundary, so lockstep ordering suffices.
__global__ __launch_bounds__(256, 2) void lstm_edge_kernel(
    const float* __restrict__ featn,
    const float* __restrict__ W_ih, const float* __restrict__ W_hh,
    const float* __restrict__ b_ih, const float* __restrict__ b_hh,
    float* __restrict__ buf0, int N,
    const int* __restrict__ src, const int* __restrict__ dst,
    const float* __restrict__ ew, float* __restrict__ deg,
    int* __restrict__ cnt, int* __restrict__ pos, int E) {
  __shared__ float hlds[256];
  const int b = blockIdx.x;
  const int g = b / 5, r = b - g * 5;
  if (r < 4) {
    // ---- LSTM branch ----
    const int tid = (g * 4 + r) * 256 + (int)threadIdx.x;
    int node = tid >> 4;
    const bool store = node < N;
    if (node >= N) node = N - 1;  // clamp: keep wave shape, skip store
    const int j = tid & 15;

    float4 wia[4], wib[4];
    float4 wh0[4], wh1[4], wh2[4], wh3[4];
    float bias[4];
#pragma unroll
    for (int gg = 0; gg < 4; ++gg) {
      const int row = 16 * gg + j;
      const float4* wi = (const float4*)(W_ih + row * 8);
      wia[gg] = wi[0]; wib[gg] = wi[1];
      const float4* wh = (const float4*)(W_hh + row * 16);
      wh0[gg] = wh[0]; wh1[gg] = wh[1]; wh2[gg] = wh[2]; wh3[gg] = wh[3];
      bias[gg] = b_ih[row] + b_hh[row];
    }
    const float* grp = &hlds[threadIdx.x & ~15];

    float h = 0.0f, c = 0.0f;
    const int start = (node >= 5) ? (node - 5) : 0;
    const int nvalid = (node < 5) ? node : 5;
#pragma unroll
    for (int t = 0; t < 5; ++t) {
      float4 x0, x1;
      if (t < nvalid) {
        const float4* xr = (const float4*)(featn + (size_t)(start + t) * 8);
        x0 = xr[0]; x1 = xr[1];
      } else {
        x0 = make_float4(0.f, 0.f, 0.f, 0.f);
        x1 = x0;
      }
      hlds[threadIdx.x] = h;
      // wave-lockstep: all 16 lanes of the group wrote before any reads issue
      float4 hb0 = ((const float4*)grp)[0];
      float4 hb1 = ((const float4*)grp)[1];
      float4 hb2 = ((const float4*)grp)[2];
      float4 hb3 = ((const float4*)grp)[3];
      float g0 = bias[0], g1 = bias[1], g2 = bias[2], g3 = bias[3];
      g0 += dot4(wia[0], x0.x, x0.y, x0.z, x0.w) + dot4(wib[0], x1.x, x1.y, x1.z, x1.w);
      g1 += dot4(wia[1], x0.x, x0.y, x0.z, x0.w) + dot4(wib[1], x1.x, x1.y, x1.z, x1.w);
      g2 += dot4(wia[2], x0.x, x0.y, x0.z, x0.w) + dot4(wib[2], x1.x, x1.y, x1.z, x1.w);
      g3 += dot4(wia[3], x0.x, x0.y, x0.z, x0.w) + dot4(wib[3], x1.x, x1.y, x1.z, x1.w);
      g0 += dot44(wh0[0], hb0) + dot44(wh1[0], hb1) + dot44(wh2[0], hb2) + dot44(wh3[0], hb3);
      g1 += dot44(wh0[1], hb0) + dot44(wh1[1], hb1) + dot44(wh2[1], hb2) + dot44(wh3[1], hb3);
      g2 += dot44(wh0[2], hb0) + dot44(wh1[2], hb1) + dot44(wh2[2], hb2) + dot44(wh3[2], hb3);
      g3 += dot44(wh0[3], hb0) + dot44(wh1[3], hb1) + dot44(wh2[3], hb2) + dot44(wh3[3], hb3);
      const float ig = sigmoidf_(g0);
      const float fg = sigmoidf_(g1);
      const float gg2 = tanh_fast(g2);
      const float og = sigmoidf_(g3);
      c = fg * c + ig * gg2;
      h = og * tanh_fast(c);
    }
    if (store) buf0[(size_t)node * 24 + 8 + j] = h;
  } else {
    // ---- edge branch: 1024 consecutive edges per block, 4 per thread ----
    const int base = g * 1024 + (int)threadIdx.x;
    const int lane = threadIdx.x & 63;
    int dv[4], sv[4];
    float wv[4];
    bool v[4];
#pragma unroll
    for (int k = 0; k < 4; ++k) {
      const int e = base + k * 256;
      v[k] = e < E;
      dv[k] = v[k] ? dst[e] : 0;
      sv[k] = v[k] ? src[e] : -1;
      wv[k] = v[k] ? ew[e] : 0.0f;
    }
    int p[4];
#pragma unroll
    for (int k = 0; k < 4; ++k)
      if (v[k]) p[k] = atomicAdd(&cnt[dv[k]], 1);
    // deg segmented reduction (VALU/shfl) overlaps the atomic round-trips
#pragma unroll
    for (int k = 0; k < 4; ++k) {
      int s = sv[k];
      float acc = wv[k];
      int sprev = __shfl_up(s, 1, 64);
      unsigned f = (lane == 0 || sprev != s) ? 1u : 0u;
#pragma unroll
      for (int d = 1; d < 64; d <<= 1) {
        float o = __shfl_up(acc, d, 64);
        unsigned fo = __shfl_up(f, d, 64);
        if (lane >= d) {
          if (!f) acc += o;
          f |= fo;
        }
      }
      int snext = __shfl_down(s, 1, 64);
      bool tail = (lane == 63) || (snext != s);
      if (v[k] && tail && s >= 0) atomicAdd(&deg[s], acc);
    }
#pragma unroll
    for (int k = 0; k < 4; ++k)
      if (v[k]) pos[base + k * 256] = p[k];
  }
}

// ---- 3-stage parallel exclusive scan of cnt[N] -> rowptr[N+1] ----
__global__ void scan_block_kernel(const int* __restrict__ cnt, int* __restrict__ rowptr,
                                  int* __restrict__ blocksum, int N) {
  __shared__ int sd[256];
  const int t = threadIdx.x;
  const int base = blockIdx.x * 1024 + t * 4;
  int c0 = 0, c1 = 0, c2 = 0, c3 = 0;
  if (base + 3 < N) {
    int4 v = *(const int4*)(cnt + base);
    c0 = v.x; c1 = v.y; c2 = v.z; c3 = v.w;
  } else {
    if (base < N) c0 = cnt[base];
    if (base + 1 < N) c1 = cnt[base + 1];
    if (base + 2 < N) c2 = cnt[base + 2];
  }
  int s = c0 + c1 + c2 + c3;
  sd[t] = s;
  __syncthreads();
  for (int d = 1; d < 256; d <<= 1) {
    int v = (t >= d) ? sd[t - d] : 0;
    __syncthreads();
    sd[t] += v;
    __syncthreads();
  }
  if (t == 255) blocksum[blockIdx.x] = sd[255];
  int p = sd[t] - s;  // exclusive
  if (base < N)     { rowptr[base] = p;     p += c0; }
  if (base + 1 < N) { rowptr[base + 1] = p; p += c1; }
  if (base + 2 < N) { rowptr[base + 2] = p; p += c2; }
  if (base + 3 < N) { rowptr[base + 3] = p; }
}

__global__ void scan_top_kernel(int* __restrict__ blocksum, int nb) {
  __shared__ int sd[256];
  const int t = threadIdx.x;
  const int chunk = (nb + 255) / 256;
  int lo = t * chunk, hi = lo + chunk;
  if (lo > nb) lo = nb;
  if (hi > nb) hi = nb;
  int s = 0;
  for (int i = lo; i < hi; ++i) s += blocksum[i];
  sd[t] = s;
  __syncthreads();
  for (int d = 1; d < 256; d <<= 1) {
    int v = (t >= d) ? sd[t - d] : 0;
    __syncthreads();
    sd[t] += v;
    __syncthreads();
  }
  int run = sd[t] - s;
  for (int i = lo; i < hi; ++i) { int v = blocksum[i]; blocksum[i] = run; run += v; }
}

__global__ void scan_add_kernel(int* __restrict__ rowptr, const int* __restrict__ blocksum,
                                int N, int E) {
  const int off = blocksum[blockIdx.x];
  const int base = blockIdx.x * 1024 + threadIdx.x * 4;
#pragma unroll
  for (int k = 0; k < 4; ++k)
    if (base + k < N) rowptr[base + k] += off;
  if (blockIdx.x == 0 && threadIdx.x == 0) rowptr[N] = E;
}

// CSR fill, no atomics: slot precomputed as rowptr[dst] + pos
__global__ void fill_kernel(const int* __restrict__ src, const int* __restrict__ dst,
                            const float* __restrict__ w, const float* __restrict__ deg,
                            const int* __restrict__ rowptr, const int* __restrict__ pos,
                            int2* __restrict__ epk, int E) {
  int e = blockIdx.x * blockDim.x + threadIdx.x;
  if (e >= E) return;
  int d = dst[e], s = src[e];
  int idx = rowptr[d] + pos[e];
  int2 pk;
  pk.x = s;
  pk.y = __float_as_int(w[e] * rsqrtf(deg[s] * deg[d]));
  epk[idx] = pk;
}

// M[row,:] = X[row,:] @ W (+bias, leaky-relu if BIASACT); DOUT/4 threads/row
template <int DIN, int DOUT, bool BIASACT>
__global__ void gemm_kernel(const float* __restrict__ X, const float* __restrict__ W,
                            const float* __restrict__ bias, float* __restrict__ M, int N) {
  constexpr int SUBS = DOUT / 4;
  int gid = blockIdx.x * blockDim.x + threadIdx.x;
  int row = gid / SUBS, sub = gid % SUBS;
  if (row >= N) return;
  const float* xr = X + (size_t)row * DIN;
  const float4* W4 = (const float4*)W;
  float4 acc = make_float4(0.f, 0.f, 0.f, 0.f);
#pragma unroll
  for (int k = 0; k < DIN; ++k) {
    float xk = xr[k];
    float4 w4 = W4[k * SUBS + sub];
    acc.x += xk * w4.x; acc.y += xk * w4.y; acc.z += xk * w4.z; acc.w += xk * w4.w;
  }
  if (BIASACT) {
    float4 b4 = ((const float4*)bias)[sub];
    acc.x += b4.x; acc.y += b4.y; acc.z += b4.z; acc.w += b4.w;
    acc.x = (acc.x >= 0.f) ? acc.x : 0.01f * acc.x;
    acc.y = (acc.y >= 0.f) ? acc.y : 0.01f * acc.y;
    acc.z = (acc.z >= 0.f) ? acc.z : 0.01f * acc.z;
    acc.w = (acc.w >= 0.f) ? acc.w : 0.01f * acc.w;
  }
  ((float4*)M)[(size_t)row * SUBS + sub] = acc;
}

// out[row,sub*4..] = (opt act)( sum_e w_e * m[col_e, sub*4..] (+ opt bias) )
// unroll-4: 4 independent epk->m4 chains in flight (was 1 -> latency-bound)
template <int DOUT, bool BIAS, bool ACT>
__global__ void gather_kernel(const float* __restrict__ m, const int* __restrict__ rowptr,
                              const int2* __restrict__ epk, const float* __restrict__ bias,
                              float* __restrict__ out, int N) {
  constexpr int SUBS = DOUT / 4;
  int gid = blockIdx.x * blockDim.x + threadIdx.x;
  int row = gid / SUBS, sub = gid % SUBS;
  if (row >= N) return;
  const int lo = rowptr[row], hi = rowptr[row + 1];
  const float4* m4 = (const float4*)m;
  float4 a0 = make_float4(0.f, 0.f, 0.f, 0.f);
  float4 a1 = make_float4(0.f, 0.f, 0.f, 0.f);
  int e = lo;
  for (; e + 4 <= hi; e += 4) {
    int2 p0 = epk[e], p1 = epk[e + 1], p2 = epk[e + 2], p3 = epk[e + 3];
    float4 v0 = m4[(size_t)p0.x * SUBS + sub];
    float4 v1 = m4[(size_t)p1.x * SUBS + sub];
    float4 v2 = m4[(size_t)p2.x * SUBS + sub];
    float4 v3 = m4[(size_t)p3.x * SUBS + sub];
    float w0 = __int_as_float(p0.y), w1 = __int_as_float(p1.y);
    float w2 = __int_as_float(p2.y), w3 = __int_as_float(p3.y);
    a0.x += w0 * v0.x; a0.y += w0 * v0.y; a0.z += w0 * v0.z; a0.w += w0 * v0.w;
    a1.x += w1 * v1.x; a1.y += w1 * v1.y; a1.z += w1 * v1.z; a1.w += w1 * v1.w;
    a0.x += w2 * v2.x; a0.y += w2 * v2.y; a0.z += w2 * v2.z; a0.w += w2 * v2.w;
    a1.x += w3 * v3.x; a1.y += w3 * v3.y; a1.z += w3 * v3.z; a1.w += w3 * v3.w;
  }
  for (; e < hi; ++e) {
    int2 pk = epk[e];
    float w = __int_as_float(pk.y);
    float4 v = m4[(size_t)pk.x * SUBS + sub];
    a0.x += w * v.x; a0.y += w * v.y; a0.z += w * v.z; a0.w += w * v.w;
  }
  float4 acc = make_float4(a0.x + a1.x, a0.y + a1.y, a0.z + a1.z, a0.w + a1.w);
  if (BIAS) {
    float4 b4 = ((const float4*)bias)[sub];
    acc.x += b4.x; acc.y += b4.y; acc.z += b4.z; acc.w += b4.w;
  }
  if (ACT) {
    acc.x = (acc.x >= 0.f) ? acc.x : 0.01f * acc.x;
    acc.y = (acc.y >= 0.f) ? acc.y : 0.01f * acc.y;
    acc.z = (acc.z >= 0.f) ? acc.z : 0.01f * acc.z;
    acc.w = (acc.w >= 0.f) ? acc.w : 0.01f * acc.w;
  }
  ((float4*)out)[(size_t)row * SUBS + sub] = acc;
}

extern "C" void kernel_launch(void* const* d_in, const int* in_sizes, int n_in,
                              void* d_out, int out_size, void* d_ws, size_t ws_size,
                              hipStream_t stream) {
  const float* feat = (const float*)d_in[0];
  const int* esrc   = (const int*)d_in[1];
  const int* edst   = (const int*)d_in[2];
  const float* ew   = (const float*)d_in[3];
  const float* W_ih = (const float*)d_in[4];
  const float* W_hh = (const float*)d_in[5];
  const float* b_ih = (const float*)d_in[6];
  const float* b_hh = (const float*)d_in[7];
  const float* W0   = (const float*)d_in[8];
  const float* b0   = (const float*)d_in[9];
  const float* W1   = (const float*)d_in[10];
  const float* b1   = (const float*)d_in[11];
  const float* W2   = (const float*)d_in[12];
  const float* b2   = (const float*)d_in[13];
  const int N = in_sizes[0] / 8;
  const int E = in_sizes[1];
  float* out = (float*)d_out;

  // workspace (floats): buf0[24N] | bufM[64N] | bufA[64N] | deg[N] | rowptr[N+2] | epk[2E]
  float* buf0 = (float*)d_ws;
  float* bufM = buf0 + (size_t)N * 24;
  float* bufA = bufM + (size_t)N * 64;
  float* deg  = bufA + (size_t)N * 64;
  int* rowptr = (int*)(deg + N);
  int2* epk   = (int2*)(rowptr + N + 2);
  // aliases: cnt[N]+pos[E] in bufM (dead before gather24 writes agg24 there);
  //          agg24[24N] in bufM (dead before gemmM overwrites bufM);
  //          featn in bufA[0,8N) (dead after lstm); blocksum at bufA+16N
  int* cnt      = (int*)bufM;
  int* pos      = cnt + N;
  float* agg24  = bufM;
  float* featn  = bufA;
  int* blocksum = (int*)(bufA + (size_t)N * 16);

  const int gN = (N + BLK - 1) / BLK;
  const int gE = (E + BLK - 1) / BLK;
  const int gN16 = ((size_t)N * 16 + BLK - 1) / BLK;  // 64-wide kernels (SUBS=16)
  const int gN8  = ((size_t)N * 8 + BLK - 1) / BLK;   // 32-wide kernels (SUBS=8)
  const int gN6  = ((size_t)N * 6 + BLK - 1) / BLK;   // 24-wide gather (SUBS=6)
  const int nb = (N + 1023) / 1024;
  const int lstmBlocks = gN16;                        // 16 threads/node
  const int edgeBlocks = (E + 1023) / 1024;           // 1024 edges/block
  const int nG = ((lstmBlocks + 3) / 4 > edgeBlocks) ? (lstmBlocks + 3) / 4 : edgeBlocks;

  prep_kernel<<<gN, BLK, 0, stream>>>(feat, featn, buf0, deg, cnt, N);
  lstm_edge_kernel<<<nG * 5, BLK, 0, stream>>>(featn, W_ih, W_hh, b_ih, b_hh, buf0, N,
                                               esrc, edst, ew, deg, cnt, pos, E);
  scan_block_kernel<<<nb, 256, 0, stream>>>(cnt, rowptr, blocksum, N);
  scan_top_kernel<<<1, 256, 0, stream>>>(blocksum, nb);
  scan_add_kernel<<<nb, 256, 0, stream>>>(rowptr, blocksum, N, E);
  fill_kernel<<<gE, BLK, 0, stream>>>(esrc, edst, ew, deg, rowptr, pos, epk, E);

  // layer 0: aggregate-first (24-wide) then transform+bias+act
  gather_kernel<24, false, false><<<gN6, BLK, 0, stream>>>(buf0, rowptr, epk, nullptr, agg24, N);
  gemm_kernel<24, 64, true><<<gN16, BLK, 0, stream>>>(agg24, W0, b0, bufA, N);
  // layer 1: transform then aggregate (64-wide both ways)
  gemm_kernel<64, 64, false><<<gN16, BLK, 0, stream>>>(bufA, W1, nullptr, bufM, N);
  gather_kernel<64, true, true><<<gN16, BLK, 0, stream>>>(bufM, rowptr, epk, b1, bufA, N);
  // layer 2: transform (64->32) then aggregate (32-wide)
  gemm_kernel<64, 32, false><<<gN8, BLK, 0, stream>>>(bufA, W2, nullptr, bufM, N);
  gather_kernel<32, true, false><<<gN8, BLK, 0, stream>>>(bufM, rowptr, epk, b2, out, N);
}

// Round 8
// 325.772 us; speedup vs baseline: 7.1507x; 1.0979x over previous
//
#include <hip/hip_runtime.h>

#define DEVINL __device__ __forceinline__

static constexpr int BLK = 256;

DEVINL float sigmoidf_(float x) { return 1.0f / (1.0f + __expf(-x)); }
// stable tanh: large +x -> exp=inf -> 1-0 = 1; large -x -> exp=0 -> 1-2 = -1
DEVINL float tanh_fast(float x) { return 1.0f - 2.0f / (__expf(2.0f * x) + 1.0f); }

DEVINL float dot4(float4 w, float a, float b, float c, float d) {
  return w.x * a + w.y * b + w.z * c + w.w * d;
}
DEVINL float dot44(float4 w, float4 h) {
  return w.x * h.x + w.y * h.y + w.z * h.z + w.w * h.w;
}

// ---- bf16 pack/unpack (RNE; finite values only) ----
DEVINL unsigned bfr_(float f) {
  unsigned u = __float_as_uint(f);
  return (u + 0x7fffu + ((u >> 16) & 1u)) >> 16;
}
DEVINL unsigned pk_bf16(float a, float b) { return bfr_(a) | (bfr_(b) << 16); }
DEVINL float blo_(unsigned u) { return __uint_as_float(u << 16); }
DEVINL float bhi_(unsigned u) { return __uint_as_float(u & 0xffff0000u); }
DEVINL void fma8(float* a, uint4 v, float w) {
  a[0] += w * blo_(v.x); a[1] += w * bhi_(v.x);
  a[2] += w * blo_(v.y); a[3] += w * bhi_(v.y);
  a[4] += w * blo_(v.z); a[5] += w * bhi_(v.z);
  a[6] += w * blo_(v.w); a[7] += w * bhi_(v.w);
}

// fused: zero deg/cnt + row-normalize feat -> featn and buf0 cols [0,8)
__global__ void prep_kernel(const float* __restrict__ feat, float* __restrict__ featn,
                            float* __restrict__ buf0, float* __restrict__ deg,
                            int* __restrict__ cnt, int N) {
  int n = blockIdx.x * blockDim.x + threadIdx.x;
  if (n >= N) return;
  deg[n] = 0.0f;
  cnt[n] = 0;
  const float4* fp = (const float4*)(feat + (size_t)n * 8);
  float4 a = fp[0], b = fp[1];
  float s = a.x + a.y + a.z + a.w + b.x + b.y + b.z + b.w;
  float r = 1.0f / s;
  a.x *= r; a.y *= r; a.z *= r; a.w *= r;
  b.x *= r; b.y *= r; b.z *= r; b.w *= r;
  float4* on = (float4*)(featn + (size_t)n * 8);
  on[0] = a; on[1] = b;
  float4* o0 = (float4*)(buf0 + (size_t)n * 24);
  o0[0] = a; o0[1] = b;
}

// Fused LSTM + edge pass, 4:1 block interleave (atomic-latency edge waves hide
// under VALU-bound LSTM waves). LSTM h-broadcast via wave-internal LDS.
__global__ __launch_bounds__(256, 2) void lstm_edge_kernel(
    const float* __restrict__ featn,
    const float* __restrict__ W_ih, const float* __restrict__ W_hh,
    const float* __restrict__ b_ih, const float* __restrict__ b_hh,
    float* __restrict__ buf0, int N,
    const int* __restrict__ src, const int* __restrict__ dst,
    const float* __restrict__ ew, float* __restrict__ deg,
    int* __restrict__ cnt, int* __restrict__ pos, int E) {
  __shared__ float hlds[256];
  const int b = blockIdx.x;
  const int g = b / 5, r = b - g * 5;
  if (r < 4) {
    // ---- LSTM branch ----
    const int tid = (g * 4 + r) * 256 + (int)threadIdx.x;
    int node = tid >> 4;
    const bool store = node < N;
    if (node >= N) node = N - 1;  // clamp: keep wave shape, skip store
    const int j = tid & 15;

    float4 wia[4], wib[4];
    float4 wh0[4], wh1[4], wh2[4], wh3[4];
    float bias[4];
#pragma unroll
    for (int gg = 0; gg < 4; ++gg) {
      const int row = 16 * gg + j;
      const float4* wi = (const float4*)(W_ih + row * 8);
      wia[gg] = wi[0]; wib[gg] = wi[1];
      const float4* wh = (const float4*)(W_hh + row * 16);
      wh0[gg] = wh[0]; wh1[gg] = wh[1]; wh2[gg] = wh[2]; wh3[gg] = wh[3];
      bias[gg] = b_ih[row] + b_hh[row];
    }
    const float* grp = &hlds[threadIdx.x & ~15];

    float h = 0.0f, c = 0.0f;
    const int start = (node >= 5) ? (node - 5) : 0;
    const int nvalid = (node < 5) ? node : 5;
#pragma unroll
    for (int t = 0; t < 5; ++t) {
      float4 x0, x1;
      if (t < nvalid) {
        const float4* xr = (const float4*)(featn + (size_t)(start + t) * 8);
        x0 = xr[0]; x1 = xr[1];
      } else {
        x0 = make_float4(0.f, 0.f, 0.f, 0.f);
        x1 = x0;
      }
      hlds[threadIdx.x] = h;
      // wave-lockstep: all 16 lanes of the group wrote before any reads issue
      float4 hb0 = ((const float4*)grp)[0];
      float4 hb1 = ((const float4*)grp)[1];
      float4 hb2 = ((const float4*)grp)[2];
      float4 hb3 = ((const float4*)grp)[3];
      float g0 = bias[0], g1 = bias[1], g2 = bias[2], g3 = bias[3];
      g0 += dot4(wia[0], x0.x, x0.y, x0.z, x0.w) + dot4(wib[0], x1.x, x1.y, x1.z, x1.w);
      g1 += dot4(wia[1], x0.x, x0.y, x0.z, x0.w) + dot4(wib[1], x1.x, x1.y, x1.z, x1.w);
      g2 += dot4(wia[2], x0.x, x0.y, x0.z, x0.w) + dot4(wib[2], x1.x, x1.y, x1.z, x1.w);
      g3 += dot4(wia[3], x0.x, x0.y, x0.z, x0.w) + dot4(wib[3], x1.x, x1.y, x1.z, x1.w);
      g0 += dot44(wh0[0], hb0) + dot44(wh1[0], hb1) + dot44(wh2[0], hb2) + dot44(wh3[0], hb3);
      g1 += dot44(wh0[1], hb0) + dot44(wh1[1], hb1) + dot44(wh2[1], hb2) + dot44(wh3[1], hb3);
      g2 += dot44(wh0[2], hb0) + dot44(wh1[2], hb1) + dot44(wh2[2], hb2) + dot44(wh3[2], hb3);
      g3 += dot44(wh0[3], hb0) + dot44(wh1[3], hb1) + dot44(wh2[3], hb2) + dot44(wh3[3], hb3);
      const float ig = sigmoidf_(g0);
      const float fg = sigmoidf_(g1);
      const float gg2 = tanh_fast(g2);
      const float og = sigmoidf_(g3);
      c = fg * c + ig * gg2;
      h = og * tanh_fast(c);
    }
    if (store) buf0[(size_t)node * 24 + 8 + j] = h;
  } else {
    // ---- edge branch: 1024 consecutive edges per block, 4 per thread ----
    const int base = g * 1024 + (int)threadIdx.x;
    const int lane = threadIdx.x & 63;
    int dv[4], sv[4];
    float wv[4];
    bool v[4];
#pragma unroll
    for (int k = 0; k < 4; ++k) {
      const int e = base + k * 256;
      v[k] = e < E;
      dv[k] = v[k] ? dst[e] : 0;
      sv[k] = v[k] ? src[e] : -1;
      wv[k] = v[k] ? ew[e] : 0.0f;
    }
    int p[4];
#pragma unroll
    for (int k = 0; k < 4; ++k)
      if (v[k]) p[k] = atomicAdd(&cnt[dv[k]], 1);
    // deg segmented reduction (VALU/shfl) overlaps the atomic round-trips
#pragma unroll
    for (int k = 0; k < 4; ++k) {
      int s = sv[k];
      float acc = wv[k];
      int sprev = __shfl_up(s, 1, 64);
      unsigned f = (lane == 0 || sprev != s) ? 1u : 0u;
#pragma unroll
      for (int d = 1; d < 64; d <<= 1) {
        float o = __shfl_up(acc, d, 64);
        unsigned fo = __shfl_up(f, d, 64);
        if (lane >= d) {
          if (!f) acc += o;
          f |= fo;
        }
      }
      int snext = __shfl_down(s, 1, 64);
      bool tail = (lane == 63) || (snext != s);
      if (v[k] && tail && s >= 0) atomicAdd(&deg[s], acc);
    }
#pragma unroll
    for (int k = 0; k < 4; ++k)
      if (v[k]) pos[base + k * 256] = p[k];
  }
}

// ---- 3-stage parallel exclusive scan of cnt[N] -> rowptr[N+1] ----
__global__ void scan_block_kernel(const int* __restrict__ cnt, int* __restrict__ rowptr,
                                  int* __restrict__ blocksum, int N) {
  __shared__ int sd[256];
  const int t = threadIdx.x;
  const int base = blockIdx.x * 1024 + t * 4;
  int c0 = 0, c1 = 0, c2 = 0, c3 = 0;
  if (base + 3 < N) {
    int4 v = *(const int4*)(cnt + base);
    c0 = v.x; c1 = v.y; c2 = v.z; c3 = v.w;
  } else {
    if (base < N) c0 = cnt[base];
    if (base + 1 < N) c1 = cnt[base + 1];
    if (base + 2 < N) c2 = cnt[base + 2];
  }
  int s = c0 + c1 + c2 + c3;
  sd[t] = s;
  __syncthreads();
  for (int d = 1; d < 256; d <<= 1) {
    int v = (t >= d) ? sd[t - d] : 0;
    __syncthreads();
    sd[t] += v;
    __syncthreads();
  }
  if (t == 255) blocksum[blockIdx.x] = sd[255];
  int p = sd[t] - s;  // exclusive
  if (base < N)     { rowptr[base] = p;     p += c0; }
  if (base + 1 < N) { rowptr[base + 1] = p; p += c1; }
  if (base + 2 < N) { rowptr[base + 2] = p; p += c2; }
  if (base + 3 < N) { rowptr[base + 3] = p; }
}

__global__ void scan_top_kernel(int* __restrict__ blocksum, int nb) {
  __shared__ int sd[256];
  const int t = threadIdx.x;
  const int chunk = (nb + 255) / 256;
  int lo = t * chunk, hi = lo + chunk;
  if (lo > nb) lo = nb;
  if (hi > nb) hi = nb;
  int s = 0;
  for (int i = lo; i < hi; ++i) s += blocksum[i];
  sd[t] = s;
  __syncthreads();
  for (int d = 1; d < 256; d <<= 1) {
    int v = (t >= d) ? sd[t - d] : 0;
    __syncthreads();
    sd[t] += v;
    __syncthreads();
  }
  int run = sd[t] - s;
  for (int i = lo; i < hi; ++i) { int v = blocksum[i]; blocksum[i] = run; run += v; }
}

__global__ void scan_add_kernel(int* __restrict__ rowptr, const int* __restrict__ blocksum,
                                int N, int E) {
  const int off = blocksum[blockIdx.x];
  const int base = blockIdx.x * 1024 + threadIdx.x * 4;
#pragma unroll
  for (int k = 0; k < 4; ++k)
    if (base + k < N) rowptr[base + k] += off;
  if (blockIdx.x == 0 && threadIdx.x == 0) rowptr[N] = E;
}

// CSR fill, no atomics: slot precomputed as rowptr[dst] + pos
__global__ void fill_kernel(const int* __restrict__ src, const int* __restrict__ dst,
                            const float* __restrict__ w, const float* __restrict__ deg,
                            const int* __restrict__ rowptr, const int* __restrict__ pos,
                            int2* __restrict__ epk, int E) {
  int e = blockIdx.x * blockDim.x + threadIdx.x;
  if (e >= E) return;
  int d = dst[e], s = src[e];
  int idx = rowptr[d] + pos[e];
  int2 pk;
  pk.x = s;
  pk.y = __float_as_int(w[e] * rsqrtf(deg[s] * deg[d]));
  epk[idx] = pk;
}

// M[row,:] = X[row,:] @ W (+bias, leaky-relu); fp32 out; DOUT/4 threads/row
template <int DIN, int DOUT, bool BIASACT>
__global__ void gemm_kernel(const float* __restrict__ X, const float* __restrict__ W,
                            const float* __restrict__ bias, float* __restrict__ M, int N) {
  constexpr int SUBS = DOUT / 4;
  int gid = blockIdx.x * blockDim.x + threadIdx.x;
  int row = gid / SUBS, sub = gid % SUBS;
  if (row >= N) return;
  const float* xr = X + (size_t)row * DIN;
  const float4* W4 = (const float4*)W;
  float4 acc = make_float4(0.f, 0.f, 0.f, 0.f);
#pragma unroll
  for (int k = 0; k < DIN; ++k) {
    float xk = xr[k];
    float4 w4 = W4[k * SUBS + sub];
    acc.x += xk * w4.x; acc.y += xk * w4.y; acc.z += xk * w4.z; acc.w += xk * w4.w;
  }
  if (BIASACT) {
    float4 b4 = ((const float4*)bias)[sub];
    acc.x += b4.x; acc.y += b4.y; acc.z += b4.z; acc.w += b4.w;
    acc.x = (acc.x >= 0.f) ? acc.x : 0.01f * acc.x;
    acc.y = (acc.y >= 0.f) ? acc.y : 0.01f * acc.y;
    acc.z = (acc.z >= 0.f) ? acc.z : 0.01f * acc.z;
    acc.w = (acc.w >= 0.f) ? acc.w : 0.01f * acc.w;
  }
  ((float4*)M)[(size_t)row * SUBS + sub] = acc;
}

// M[row,:] = X[row,:] @ W packed to bf16 (2/u32, RNE); DOUT/4 threads/row
template <int DIN, int DOUT>
__global__ void gemm_bf16_kernel(const float* __restrict__ X, const float* __restrict__ W,
                                 uint2* __restrict__ M, int N) {
  constexpr int SUBS = DOUT / 4;
  int gid = blockIdx.x * blockDim.x + threadIdx.x;
  int row = gid / SUBS, sub = gid % SUBS;
  if (row >= N) return;
  const float* xr = X + (size_t)row * DIN;
  const float4* W4 = (const float4*)W;
  float4 acc = make_float4(0.f, 0.f, 0.f, 0.f);
#pragma unroll
  for (int k = 0; k < DIN; ++k) {
    float xk = xr[k];
    float4 w4 = W4[k * SUBS + sub];
    acc.x += xk * w4.x; acc.y += xk * w4.y; acc.z += xk * w4.z; acc.w += xk * w4.w;
  }
  uint2 pk;
  pk.x = pk_bf16(acc.x, acc.y);
  pk.y = pk_bf16(acc.z, acc.w);
  M[(size_t)row * SUBS + sub] = pk;
}

// fp32 gather (layer 0, 24-wide): unchanged from round 6
template <int DOUT, bool BIAS, bool ACT>
__global__ void gather_kernel(const float* __restrict__ m, const int* __restrict__ rowptr,
                              const int2* __restrict__ epk, const float* __restrict__ bias,
                              float* __restrict__ out, int N) {
  constexpr int SUBS = DOUT / 4;
  int gid = blockIdx.x * blockDim.x + threadIdx.x;
  int row = gid / SUBS, sub = gid % SUBS;
  if (row >= N) return;
  const int lo = rowptr[row], hi = rowptr[row + 1];
  const float4* m4 = (const float4*)m;
  float4 a0 = make_float4(0.f, 0.f, 0.f, 0.f);
  float4 a1 = make_float4(0.f, 0.f, 0.f, 0.f);
  int e = lo;
  for (; e + 4 <= hi; e += 4) {
    int2 p0 = epk[e], p1 = epk[e + 1], p2 = epk[e + 2], p3 = epk[e + 3];
    float4 v0 = m4[(size_t)p0.x * SUBS + sub];
    float4 v1 = m4[(size_t)p1.x * SUBS + sub];
    float4 v2 = m4[(size_t)p2.x * SUBS + sub];
    float4 v3 = m4[(size_t)p3.x * SUBS + sub];
    float w0 = __int_as_float(p0.y), w1 = __int_as_float(p1.y);
    float w2 = __int_as_float(p2.y), w3 = __int_as_float(p3.y);
    a0.x += w0 * v0.x; a0.y += w0 * v0.y; a0.z += w0 * v0.z; a0.w += w0 * v0.w;
    a1.x += w1 * v1.x; a1.y += w1 * v1.y; a1.z += w1 * v1.z; a1.w += w1 * v1.w;
    a0.x += w2 * v2.x; a0.y += w2 * v2.y; a0.z += w2 * v2.z; a0.w += w2 * v2.w;
    a1.x += w3 * v3.x; a1.y += w3 * v3.y; a1.z += w3 * v3.z; a1.w += w3 * v3.w;
  }
  for (; e < hi; ++e) {
    int2 pk = epk[e];
    float w = __int_as_float(pk.y);
    float4 v = m4[(size_t)pk.x * SUBS + sub];
    a0.x += w * v.x; a0.y += w * v.y; a0.z += w * v.z; a0.w += w * v.w;
  }
  float4 acc = make_float4(a0.x + a1.x, a0.y + a1.y, a0.z + a1.z, a0.w + a1.w);
  if (BIAS) {
    float4 b4 = ((const float4*)bias)[sub];
    acc.x += b4.x; acc.y += b4.y; acc.z += b4.z; acc.w += b4.w;
  }
  if (ACT) {
    acc.x = (acc.x >= 0.f) ? acc.x : 0.01f * acc.x;
    acc.y = (acc.y >= 0.f) ? acc.y : 0.01f * acc.y;
    acc.z = (acc.z >= 0.f) ? acc.z : 0.01f * acc.z;
    acc.w = (acc.w >= 0.f) ? acc.w : 0.01f * acc.w;
  }
  ((float4*)out)[(size_t)row * SUBS + sub] = acc;
}

// bf16 gather: W features/row, 8 bf16 per lane (one uint4 = 16B per edge-load).
// out fp32 (+bias, opt leaky-relu). Unroll-4 for 4 independent load chains.
template <int W, bool ACT>
__global__ void gather_bf16_kernel(const uint4* __restrict__ m, const int* __restrict__ rowptr,
                                   const int2* __restrict__ epk, const float* __restrict__ bias,
                                   float* __restrict__ out, int N) {
  constexpr int SUBS = W / 8;
  int gid = blockIdx.x * blockDim.x + threadIdx.x;
  int row = gid / SUBS, sub = gid % SUBS;
  if (row >= N) return;
  const int lo = rowptr[row], hi = rowptr[row + 1];
  float acc[8];
#pragma unroll
  for (int k = 0; k < 8; ++k) acc[k] = 0.0f;
  int e = lo;
  for (; e + 4 <= hi; e += 4) {
    int2 p0 = epk[e], p1 = epk[e + 1], p2 = epk[e + 2], p3 = epk[e + 3];
    uint4 v0 = m[(size_t)p0.x * SUBS + sub];
    uint4 v1 = m[(size_t)p1.x * SUBS + sub];
    uint4 v2 = m[(size_t)p2.x * SUBS + sub];
    uint4 v3 = m[(size_t)p3.x * SUBS + sub];
    fma8(acc, v0, __int_as_float(p0.y));
    fma8(acc, v1, __int_as_float(p1.y));
    fma8(acc, v2, __int_as_float(p2.y));
    fma8(acc, v3, __int_as_float(p3.y));
  }
  for (; e < hi; ++e) {
    int2 pk = epk[e];
    uint4 v = m[(size_t)pk.x * SUBS + sub];
    fma8(acc, v, __int_as_float(pk.y));
  }
#pragma unroll
  for (int k = 0; k < 8; ++k) acc[k] += bias[sub * 8 + k];
  if (ACT) {
#pragma unroll
    for (int k = 0; k < 8; ++k) acc[k] = (acc[k] >= 0.f) ? acc[k] : 0.01f * acc[k];
  }
  float4* o4 = (float4*)(out + (size_t)row * W + sub * 8);
  o4[0] = make_float4(acc[0], acc[1], acc[2], acc[3]);
  o4[1] = make_float4(acc[4], acc[5], acc[6], acc[7]);
}

extern "C" void kernel_launch(void* const* d_in, const int* in_sizes, int n_in,
                              void* d_out, int out_size, void* d_ws, size_t ws_size,
                              hipStream_t stream) {
  const float* feat = (const float*)d_in[0];
  const int* esrc   = (const int*)d_in[1];
  const int* edst   = (const int*)d_in[2];
  const float* ew   = (const float*)d_in[3];
  const float* W_ih = (const float*)d_in[4];
  const float* W_hh = (const float*)d_in[5];
  const float* b_ih = (const float*)d_in[6];
  const float* b_hh = (const float*)d_in[7];
  const float* W0   = (const float*)d_in[8];
  const float* b0   = (const float*)d_in[9];
  const float* W1   = (const float*)d_in[10];
  const float* b1   = (const float*)d_in[11];
  const float* W2   = (const float*)d_in[12];
  const float* b2   = (const float*)d_in[13];
  const int N = in_sizes[0] / 8;
  const int E = in_sizes[1];
  float* out = (float*)d_out;

  // workspace (floats): buf0[24N] | bufM[64N] | bufA[64N] | deg[N] | rowptr[N+2] | epk[2E]
  float* buf0 = (float*)d_ws;
  float* bufM = buf0 + (size_t)N * 24;
  float* bufA = bufM + (size_t)N * 64;
  float* deg  = bufA + (size_t)N * 64;
  int* rowptr = (int*)(deg + N);
  int2* epk   = (int2*)(rowptr + N + 2);
  // aliases (all in bufM, each dead before the next use):
  //   cnt[N]+pos[E] (through fill) -> agg24[24N] (through gemm0)
  //   -> bf16 message buffers (gemm1/gather1: 64-wide=32N u32; gemm2/gather2: 32-wide=16N u32)
  int* cnt      = (int*)bufM;
  int* pos      = cnt + N;
  float* agg24  = bufM;
  float* featn  = bufA;
  int* blocksum = (int*)(bufA + (size_t)N * 16);

  const int gN = (N + BLK - 1) / BLK;
  const int gE = (E + BLK - 1) / BLK;
  const int gN16 = ((size_t)N * 16 + BLK - 1) / BLK;  // SUBS=16 kernels
  const int gN8  = ((size_t)N * 8 + BLK - 1) / BLK;   // SUBS=8 kernels
  const int gN6  = ((size_t)N * 6 + BLK - 1) / BLK;   // 24-wide fp32 gather
  const int gN4  = ((size_t)N * 4 + BLK - 1) / BLK;   // 32-wide bf16 gather
  const int nb = (N + 1023) / 1024;
  const int lstmBlocks = gN16;                        // 16 threads/node
  const int edgeBlocks = (E + 1023) / 1024;           // 1024 edges/block
  const int nG = ((lstmBlocks + 3) / 4 > edgeBlocks) ? (lstmBlocks + 3) / 4 : edgeBlocks;

  prep_kernel<<<gN, BLK, 0, stream>>>(feat, featn, buf0, deg, cnt, N);
  lstm_edge_kernel<<<nG * 5, BLK, 0, stream>>>(featn, W_ih, W_hh, b_ih, b_hh, buf0, N,
                                               esrc, edst, ew, deg, cnt, pos, E);
  scan_block_kernel<<<nb, 256, 0, stream>>>(cnt, rowptr, blocksum, N);
  scan_top_kernel<<<1, 256, 0, stream>>>(blocksum, nb);
  scan_add_kernel<<<nb, 256, 0, stream>>>(rowptr, blocksum, N, E);
  fill_kernel<<<gE, BLK, 0, stream>>>(esrc, edst, ew, deg, rowptr, pos, epk, E);

  // layer 0 (fp32): aggregate-first (24-wide) then transform+bias+act
  gather_kernel<24, false, false><<<gN6, BLK, 0, stream>>>(buf0, rowptr, epk, nullptr, agg24, N);
  gemm_kernel<24, 64, true><<<gN16, BLK, 0, stream>>>(agg24, W0, b0, bufA, N);
  // layer 1 (bf16 messages): transform -> bf16, aggregate 8 bf16/lane, +b1+act
  gemm_bf16_kernel<64, 64><<<gN16, BLK, 0, stream>>>(bufA, W1, (uint2*)bufM, N);
  gather_bf16_kernel<64, true><<<gN8, BLK, 0, stream>>>((const uint4*)bufM, rowptr, epk, b1, bufA, N);
  // layer 2 (bf16 messages): transform 64->32 -> bf16, aggregate, +b2
  gemm_bf16_kernel<64, 32><<<gN8, BLK, 0, stream>>>(bufA, W2, (uint2*)bufM, N);
  gather_bf16_kernel<32, false><<<gN4, BLK, 0, stream>>>((const uint4*)bufM, rowptr, epk, b2, out, N);
}